// Round 1
// baseline (867.774 us; speedup 1.0000x reference)
//
#include <hip/hip_runtime.h>
#include <math.h>

// ---------------------------------------------------------------------------
// GCN_mamba_Net: fp32 correctness-first implementation.
// N=2048 nodes, F_IN=512, D_MODEL=D_INNER=256, NHEADS=32, HDIM=8, D_ST2=8,
// CONV_DIM=272, LAYERS=8, DT_RANK=16, N_STATE=16, NUM_CLASSES=40.
// ---------------------------------------------------------------------------

__device__ __forceinline__ float softplus_f(float x) {
    // matches jax.nn.softplus: max(x,0) + log1p(exp(-|x|))
    return fmaxf(x, 0.f) + log1pf(expf(-fabsf(x)));
}
__device__ __forceinline__ float silu_f(float x) {
    return x / (1.f + expf(-x));
}

// ---------------------------------------------------------------------------
// Generic fp32 matmul: C[M,N] = A[M,K](lda) @ B[K,N](ldb).  256 thr, 64x64
// tile, BK=16, 4x4 per thread.  M%64==0, K%16==0 assumed; N guarded.
// EPI: 0 none, 1 relu, 2 gout (relu*0.9+0.1*aux), 3 allout remap.
// ---------------------------------------------------------------------------
template<int EPI>
__global__ __launch_bounds__(256) void mm_f32(
    const float* __restrict__ A, int lda,
    const float* __restrict__ B, int ldb,
    float* __restrict__ C, int ldc,
    int M, int N, int K,
    const float* __restrict__ aux, float* __restrict__ aux2)
{
    __shared__ float As[16][68];
    __shared__ float Bs[16][64];
    const int tid = threadIdx.x;
    const int row0 = blockIdx.y * 64, col0 = blockIdx.x * 64;
    const int ty = tid >> 4, tx = tid & 15;
    float acc[4][4] = {};
    for (int k0 = 0; k0 < K; k0 += 16) {
        {   // A tile 64x16, transposed store
            int r = tid >> 2, kq = tid & 3;
            float4 a4 = *reinterpret_cast<const float4*>(&A[(size_t)(row0 + r) * lda + k0 + kq * 4]);
            As[kq * 4 + 0][r] = a4.x; As[kq * 4 + 1][r] = a4.y;
            As[kq * 4 + 2][r] = a4.z; As[kq * 4 + 3][r] = a4.w;
        }
        {   // B tile 16x64
            int kk = tid >> 4, cq = tid & 15;
            int col = col0 + cq * 4;
            float4 b4 = make_float4(0.f, 0.f, 0.f, 0.f);
            if (col < N) b4 = *reinterpret_cast<const float4*>(&B[(size_t)(k0 + kk) * ldb + col]);
            *reinterpret_cast<float4*>(&Bs[kk][cq * 4]) = b4;
        }
        __syncthreads();
        #pragma unroll
        for (int kk = 0; kk < 16; ++kk) {
            float4 a4 = *reinterpret_cast<const float4*>(&As[kk][ty * 4]);
            float4 b4 = *reinterpret_cast<const float4*>(&Bs[kk][tx * 4]);
            float av[4] = {a4.x, a4.y, a4.z, a4.w};
            float bv[4] = {b4.x, b4.y, b4.z, b4.w};
            #pragma unroll
            for (int i = 0; i < 4; ++i)
                #pragma unroll
                for (int j = 0; j < 4; ++j)
                    acc[i][j] = fmaf(av[i], bv[j], acc[i][j]);
        }
        __syncthreads();
    }
    #pragma unroll
    for (int i = 0; i < 4; ++i) {
        int row = row0 + ty * 4 + i;
        #pragma unroll
        for (int j = 0; j < 4; ++j) {
            int col = col0 + tx * 4 + j;
            if (col >= N) continue;
            float v = acc[i][j];
            if (EPI == 0) {
                C[(size_t)row * ldc + col] = v;
            } else if (EPI == 1) {
                C[(size_t)row * ldc + col] = fmaxf(v, 0.f);
            } else if (EPI == 2) {
                C[(size_t)row * ldc + col] = fmaxf(v, 0.f) * 0.9f + 0.1f * aux[(size_t)row * ldc + col];
            } else if (EPI == 3) {
                int b = row & 2047, l = row >> 11;
                C[(size_t)((b << 3) + l) * 256 + col] = fmaxf(v, 0.f);
                if (l == 7) aux2[(size_t)b * 256 + col] = v;
            }
        }
    }
}

// split-K (4-way) fp32 matmul into private partial buffers (deterministic).
// N==256, M%64==0, K%64==0.
__global__ __launch_bounds__(256) void mm_f32_splitk(
    const float* __restrict__ A, int lda,
    const float* __restrict__ B, int ldb,
    float* __restrict__ psum, int M, int N, int K)
{
    __shared__ float As[16][68];
    __shared__ float Bs[16][64];
    const int tid = threadIdx.x;
    const int row0 = blockIdx.y * 64, col0 = blockIdx.x * 64;
    const int kz = blockIdx.z;
    const int kper = K >> 2;
    const int kstart = kz * kper;
    const int ty = tid >> 4, tx = tid & 15;
    float acc[4][4] = {};
    for (int k0 = kstart; k0 < kstart + kper; k0 += 16) {
        {
            int r = tid >> 2, kq = tid & 3;
            float4 a4 = *reinterpret_cast<const float4*>(&A[(size_t)(row0 + r) * lda + k0 + kq * 4]);
            As[kq * 4 + 0][r] = a4.x; As[kq * 4 + 1][r] = a4.y;
            As[kq * 4 + 2][r] = a4.z; As[kq * 4 + 3][r] = a4.w;
        }
        {
            int kk = tid >> 4, cq = tid & 15;
            float4 b4 = *reinterpret_cast<const float4*>(&B[(size_t)(k0 + kk) * ldb + col0 + cq * 4]);
            *reinterpret_cast<float4*>(&Bs[kk][cq * 4]) = b4;
        }
        __syncthreads();
        #pragma unroll
        for (int kk = 0; kk < 16; ++kk) {
            float4 a4 = *reinterpret_cast<const float4*>(&As[kk][ty * 4]);
            float4 b4 = *reinterpret_cast<const float4*>(&Bs[kk][tx * 4]);
            float av[4] = {a4.x, a4.y, a4.z, a4.w};
            float bv[4] = {b4.x, b4.y, b4.z, b4.w};
            #pragma unroll
            for (int i = 0; i < 4; ++i)
                #pragma unroll
                for (int j = 0; j < 4; ++j)
                    acc[i][j] = fmaf(av[i], bv[j], acc[i][j]);
        }
        __syncthreads();
    }
    float* Cp = psum + (size_t)kz * M * N;
    #pragma unroll
    for (int i = 0; i < 4; ++i) {
        int row = row0 + ty * 4 + i;
        #pragma unroll
        for (int j = 0; j < 4; ++j) {
            int col = col0 + tx * 4 + j;
            Cp[(size_t)row * N + col] = acc[i][j];
        }
    }
}

// combine: xi = 0.95*(p0+p1+p2+p3) + 0.05*xb.  524288 elems exact.
__global__ __launch_bounds__(256) void k_gcn_combine(
    const float* __restrict__ psum, const float* __restrict__ xb, float* __restrict__ outp)
{
    int i = blockIdx.x * 256 + threadIdx.x;
    float s = psum[i] + psum[524288 + i] + psum[2 * 524288 + i] + psum[3 * 524288 + i];
    outp[i] = 0.95f * s + 0.05f * xb[i];
}

// dt = softplus(Z[:,528+h] + bias); dA = exp(dt * (-exp(A_log[h]))).  65536 elems.
__global__ __launch_bounds__(256) void k_dtda(
    const float* __restrict__ Z, const float* __restrict__ bias,
    const float* __restrict__ A_log, float* __restrict__ dt, float* __restrict__ dA)
{
    int idx = blockIdx.x * 256 + threadIdx.x;
    if (idx >= 2048 * 32) return;
    int t = idx >> 5, h = idx & 31;
    float v = Z[(size_t)t * 560 + 528 + h] + bias[h];
    float dtv = softplus_f(v);
    float Ah = -expf(A_log[h]);
    dt[idx] = dtv;
    dA[idx] = expf(dtv * Ah);
}

// depthwise causal conv (fwd) / anti-causal (rev) + silu, split into xh/B/C.
__global__ __launch_bounds__(320) void k_conv(
    const float* __restrict__ Z, const float* __restrict__ w, const float* __restrict__ bconv,
    float* __restrict__ xhf, float* __restrict__ Bf, float* __restrict__ Cf,
    float* __restrict__ xhr, float* __restrict__ Br, float* __restrict__ Cr)
{
    int bx = blockIdx.x;               // 0..4095
    int dir = bx >> 11, t = bx & 2047;
    int c = threadIdx.x;
    if (c >= 272) return;
    float acc = bconv[c];
    #pragma unroll
    for (int k = 0; k < 4; ++k) {
        int tt = dir ? (t + 3 - k) : (t - 3 + k);
        if (tt >= 0 && tt < 2048) acc = fmaf(w[c * 4 + k], Z[(size_t)tt * 560 + 256 + c], acc);
    }
    float v = silu_f(acc);
    float* xh = dir ? xhr : xhf;
    float* B  = dir ? Br  : Bf;
    float* C  = dir ? Cr  : Cf;
    if (c < 256)       xh[(size_t)t * 256 + c] = v;
    else if (c < 264)  B[(size_t)t * 8 + (c - 256)] = v;
    else               C[(size_t)t * 8 + (c - 264)] = v;
}

// Mamba2 selective scan, 64 blocks = {dir,head}, 64 lanes = (p,n) state elems.
__global__ __launch_bounds__(64) void k_scan_m2(
    const float* __restrict__ dt, const float* __restrict__ dA,
    const float* __restrict__ xhf, const float* __restrict__ Bf, const float* __restrict__ Cf,
    const float* __restrict__ xhr, const float* __restrict__ Br, const float* __restrict__ Cr,
    const float* __restrict__ Dvec,
    float* __restrict__ yf, float* __restrict__ yr)
{
    int bid = blockIdx.x;
    int dir = bid >> 5, h = bid & 31;
    const float* xhp = dir ? xhr : xhf;
    const float* Bp  = dir ? Br  : Bf;
    const float* Cp  = dir ? Cr  : Cf;
    float* yp        = dir ? yr  : yf;
    int lane = threadIdx.x;
    int p = lane >> 3, n = lane & 7;
    float Dh = Dvec[h];
    __shared__ float dAs[128];
    __shared__ float Ps[128][8];
    __shared__ float Bs[128][8];
    __shared__ float Cs[128][8];
    __shared__ float Ys[128][8];
    float s = 0.f;
    for (int c = 0; c < 16; ++c) {
        for (int j = lane; j < 128; j += 64) {
            int t = dir ? (2047 - (c * 128 + j)) : (c * 128 + j);
            dAs[j] = dA[(size_t)t * 32 + h];
        }
        for (int j = lane; j < 1024; j += 64) {
            int i = j >> 3, e = j & 7;
            int t = dir ? (2047 - (c * 128 + i)) : (c * 128 + i);
            Ps[i][e] = dt[(size_t)t * 32 + h] * xhp[(size_t)t * 256 + h * 8 + e];
            Bs[i][e] = Bp[(size_t)t * 8 + e];
            Cs[i][e] = Cp[(size_t)t * 8 + e];
        }
        __syncthreads();
        for (int i = 0; i < 128; ++i) {
            float a = dAs[i];
            float u = Ps[i][p] * Bs[i][n];
            s = fmaf(a, s, u);
            float yv = s * Cs[i][n];
            yv += __shfl_xor(yv, 1);
            yv += __shfl_xor(yv, 2);
            yv += __shfl_xor(yv, 4);
            if (n == 0) Ys[i][p] = yv;
        }
        __syncthreads();
        for (int j = lane; j < 1024; j += 64) {
            int i = j >> 3, e = j & 7;
            int t = dir ? (2047 - (c * 128 + i)) : (c * 128 + i);
            yp[(size_t)t * 256 + h * 8 + e] = Ys[i][e] + xhp[(size_t)t * 256 + h * 8 + e] * Dh;
        }
        __syncthreads();
    }
}

// gating + per-direction RMS norm, summed: gsum = (gf*rsf + gr*rsr) * norm_w
__global__ __launch_bounds__(256) void k_gate(
    const float* __restrict__ Z, const float* __restrict__ yf, const float* __restrict__ yr,
    const float* __restrict__ nw, float* __restrict__ gsum)
{
    int t = blockIdx.x, d = threadIdx.x;
    float zv = Z[(size_t)t * 560 + d];
    float sz = silu_f(zv);
    float gf = yf[(size_t)t * 256 + d] * sz;
    float gr = yr[(size_t)t * 256 + d] * sz;
    float vf = gf * gf, vr = gr * gr;
    for (int o = 32; o > 0; o >>= 1) { vf += __shfl_down(vf, o); vr += __shfl_down(vr, o); }
    __shared__ float sfa[4], sra[4];
    __shared__ float tot[2];
    int wid = d >> 6;
    if ((d & 63) == 0) { sfa[wid] = vf; sra[wid] = vr; }
    __syncthreads();
    if (d == 0) {
        tot[0] = sfa[0] + sfa[1] + sfa[2] + sfa[3];
        tot[1] = sra[0] + sra[1] + sra[2] + sra[3];
    }
    __syncthreads();
    float inf_ = rsqrtf(tot[0] / 256.f + 1e-5f);
    float inr_ = rsqrtf(tot[1] / 256.f + 1e-5f);
    gsum[(size_t)t * 256 + d] = (gf * inf_ + gr * inr_) * nw[d];
}

// xb = relu(bn1(X)) -> feats[0]
__global__ __launch_bounds__(256) void k_xb(
    const float* __restrict__ X, const float* __restrict__ g, const float* __restrict__ b,
    float* __restrict__ outp)
{
    int i = blockIdx.x * 256 + threadIdx.x;
    int d = i & 255;
    const float sc = 0.99999500003749951f;  // 1/sqrt(1+1e-5)
    float v = X[i] * (g[d] * sc) + b[d];
    outp[i] = fmaxf(v, 0.f);
}

// GCN-mamba scan over 8 layers; delta projection (K=16) inlined; y in-place.
__global__ __launch_bounds__(256) void k_scan_gcn(
    const float* __restrict__ xdbl,   // [16384][48] (relu'd)
    const float* __restrict__ dtW,    // [16][256]
    const float* __restrict__ A_log,  // [256][16]
    const float* __restrict__ Dv,     // [256]
    float* __restrict__ feats)        // [8][2048][256], overwritten with y
{
    int b = blockIdx.x, d = threadIdx.x;
    __shared__ float xrow[8][48];
    for (int j = d; j < 384; j += 256) {
        int l = j / 48, k = j % 48;
        xrow[l][k] = xdbl[(size_t)(l * 2048 + b) * 48 + k];
    }
    __syncthreads();
    float a[16];
    #pragma unroll
    for (int n = 0; n < 16; ++n) a[n] = -expf(A_log[d * 16 + n]);
    float Dd = Dv[d];
    float s[16];
    #pragma unroll
    for (int n = 0; n < 16; ++n) s[n] = 0.f;
    for (int l = 0; l < 8; ++l) {
        float accd = 0.f;
        #pragma unroll
        for (int k = 0; k < 16; ++k) accd = fmaf(xrow[l][k], dtW[k * 256 + d], accd);
        float dl = softplus_f(accd);
        size_t r = (size_t)(l * 2048 + b) * 256 + d;
        float xv = feats[r];
        float du = dl * xv;
        float y = 0.f;
        #pragma unroll
        for (int n = 0; n < 16; ++n) {
            float dAn = expf(dl * a[n]);
            s[n] = fmaf(dAn, s[n], du * xrow[l][16 + n]);
            y = fmaf(s[n], xrow[l][32 + n], y);
        }
        feats[r] = y + xv * Dd;
    }
}

// head: output mix + bn2 + relu, y2 = output@lin2_W, log_softmax over 40.
__global__ __launch_bounds__(256) void k_head(
    const float* __restrict__ lastl, const float* __restrict__ X, const float* __restrict__ gout,
    const float* __restrict__ g2, const float* __restrict__ b2, const float* __restrict__ W2,
    float* __restrict__ out1)
{
    int b = blockIdx.x, d = threadIdx.x;
    __shared__ float ov[256];
    __shared__ float yv[40];
    const float sc = 0.99999500003749951f;
    float v = (lastl[(size_t)b * 256 + d] + X[(size_t)b * 256 + d]) * 0.5f
              + gout[(size_t)b * 256 + d] * 0.5f;
    v = v * (g2[d] * sc) + b2[d];
    ov[d] = fmaxf(v, 0.f);
    __syncthreads();
    if (d < 40) {
        float acc = 0.f;
        for (int k = 0; k < 256; ++k) acc = fmaf(ov[k], W2[k * 40 + d], acc);
        yv[d] = acc;
    }
    __syncthreads();
    if (d < 40) {
        float m = -1e30f;
        for (int j = 0; j < 40; ++j) m = fmaxf(m, yv[j]);
        float se = 0.f;
        for (int j = 0; j < 40; ++j) se += expf(yv[j] - m);
        out1[(size_t)b * 40 + d] = yv[d] - m - logf(se);
    }
}

// ---------------------------------------------------------------------------
extern "C" void kernel_launch(void* const* d_in, const int* in_sizes, int n_in,
                              void* d_out, int out_size, void* d_ws, size_t ws_size,
                              hipStream_t stream)
{
    const float* x      = (const float*)d_in[0];
    const float* adj    = (const float*)d_in[1];
    const float* lin1W  = (const float*)d_in[2];
    const float* inproj = (const float*)d_in[3];
    const float* convw  = (const float*)d_in[4];
    const float* convb  = (const float*)d_in[5];
    const float* dtbias = (const float*)d_in[6];
    const float* m2Alog = (const float*)d_in[7];
    const float* m2D    = (const float*)d_in[8];
    const float* normw  = (const float*)d_in[9];
    const float* outprj = (const float*)d_in[10];
    const float* xprojW = (const float*)d_in[11];
    const float* dtprjW = (const float*)d_in[12];
    const float* bAlog  = (const float*)d_in[13];
    const float* bD     = (const float*)d_in[14];
    const float* boutW  = (const float*)d_in[15];
    const float* bn1g   = (const float*)d_in[16];
    const float* bn1b   = (const float*)d_in[17];
    const float* bn2g   = (const float*)d_in[18];
    const float* bn2b   = (const float*)d_in[19];
    const float* lin2W  = (const float*)d_in[20];
    float* out = (float*)d_out;
    float* ws  = (float*)d_ws;

    float* X     = ws + 0;         // 2048*256
    float* Z     = ws + 524288;    // 2048*560
    float* dt    = ws + 1671168;   // 2048*32
    float* dA    = ws + 1736704;   // 2048*32
    float* xhf   = ws + 1802240;   // 2048*256
    float* Bf    = ws + 2326528;   // 2048*8
    float* Cf    = ws + 2342912;   // 2048*8
    float* xhr   = ws + 2359296;   // 2048*256
    float* Br    = ws + 2883584;   // 2048*8
    float* Cr    = ws + 2899968;   // 2048*8
    float* yf    = ws + 2916352;   // 2048*256
    float* yr    = ws + 3440640;   // 2048*256
    float* gsum  = ws + 3964928;   // 2048*256
    float* gout  = ws + 4489216;   // 2048*256
    float* feats = ws + 5013504;   // 8*2048*256
    float* xdbl  = ws + 9207808;   // 16384*48
    float* lastl = ws + 9994240;   // 2048*256
    float* psum  = ws + 10518528;  // 4*2048*256
    (void)ws_size; (void)in_sizes; (void)n_in; (void)out_size;

    dim3 blk(256);
    // 1. X = x @ lin1_W        (2048x512 @ 512x256)
    mm_f32<0><<<dim3(4, 32), blk, 0, stream>>>(x, 512, lin1W, 256, X, 256, 2048, 256, 512, nullptr, nullptr);
    // 2. Z = X @ in_proj       (2048x256 @ 256x560)
    mm_f32<0><<<dim3(9, 32), blk, 0, stream>>>(X, 256, inproj, 560, Z, 560, 2048, 560, 256, nullptr, nullptr);
    // 3. dt / dA
    k_dtda<<<dim3(256), blk, 0, stream>>>(Z, dtbias, m2Alog, dt, dA);
    // 4. conv (both directions)
    k_conv<<<dim3(4096), dim3(320), 0, stream>>>(Z, convw, convb, xhf, Bf, Cf, xhr, Br, Cr);
    // 5. bidirectional selective scan
    k_scan_m2<<<dim3(64), dim3(64), 0, stream>>>(dt, dA, xhf, Bf, Cf, xhr, Br, Cr, m2D, yf, yr);
    // 6. gate + RMS (both dirs) -> gsum
    k_gate<<<dim3(2048), blk, 0, stream>>>(Z, yf, yr, normw, gsum);
    // 7. gout = relu(gsum@out_proj)*0.9 + 0.1*X
    mm_f32<2><<<dim3(4, 32), blk, 0, stream>>>(gsum, 256, outprj, 256, gout, 256, 2048, 256, 256, X, nullptr);
    // 8. feats[0] = xb = relu(bn1(X))
    k_xb<<<dim3(2048), blk, 0, stream>>>(X, bn1g, bn1b, feats);
    // 9. GCN chain: feats[i] = 0.95*(adj@feats[i-1]) + 0.05*feats[0]
    for (int i = 1; i < 8; ++i) {
        mm_f32_splitk<<<dim3(4, 32, 4), blk, 0, stream>>>(adj, 2048, feats + (size_t)(i - 1) * 524288, 256,
                                                          psum, 2048, 256, 2048);
        k_gcn_combine<<<dim3(2048), blk, 0, stream>>>(psum, feats, feats + (size_t)i * 524288);
    }
    // 10. xdbl = relu(feats @ xproj_W)   (16384x256 @ 256x48)
    mm_f32<1><<<dim3(1, 256), blk, 0, stream>>>(feats, 256, xprojW, 48, xdbl, 48, 16384, 48, 256, nullptr, nullptr);
    // 11. GCN scan (delta proj inlined), y written in-place over feats
    k_scan_gcn<<<dim3(2048), blk, 0, stream>>>(xdbl, dtprjW, bAlog, bD, feats);
    // 12. all_out = relu(y @ outproj_W) remapped (b,l,d); raw l=7 -> lastl
    mm_f32<3><<<dim3(4, 256), blk, 0, stream>>>(feats, 256, boutW, 256, out, 256, 16384, 256, 256, nullptr, lastl);
    // 13. head: mix + bn2 + relu + lin2 + log_softmax
    k_head<<<dim3(2048), blk, 0, stream>>>(lastl, X, gout, bn2g, bn2b, lin2W, out + 4194304);
}

// Round 3
// 531.309 us; speedup vs baseline: 1.6333x; 1.6333x over previous
//
#include <hip/hip_runtime.h>
#include <math.h>

// ---------------------------------------------------------------------------
// GCN_mamba_Net: fp32, chunk-parallel Mamba2 scan.
// N=2048 nodes, F_IN=512, D_MODEL=D_INNER=256, NHEADS=32, HDIM=8, D_ST2=8,
// CONV_DIM=272, LAYERS=8, DT_RANK=16, N_STATE=16, NUM_CLASSES=40.
// ---------------------------------------------------------------------------

__device__ __forceinline__ float softplus_f(float x) {
    return fmaxf(x, 0.f) + log1pf(expf(-fabsf(x)));
}
__device__ __forceinline__ float silu_f(float x) {
    return x / (1.f + expf(-x));
}

// ---------------------------------------------------------------------------
// Generic fp32 matmul: C[M,N] = A[M,K](lda) @ B[K,N](ldb).  256 thr, 64x64
// tile, BK=16, 4x4 per thread.  M%64==0, K%16==0 assumed; N guarded.
// EPI: 0 none, 1 relu, 2 gout (relu*0.9+0.1*aux), 3 allout remap.
// ---------------------------------------------------------------------------
template<int EPI>
__global__ __launch_bounds__(256) void mm_f32(
    const float* __restrict__ A, int lda,
    const float* __restrict__ B, int ldb,
    float* __restrict__ C, int ldc,
    int M, int N, int K,
    const float* __restrict__ aux, float* __restrict__ aux2)
{
    __shared__ float As[16][68];
    __shared__ float Bs[16][64];
    const int tid = threadIdx.x;
    const int row0 = blockIdx.y * 64, col0 = blockIdx.x * 64;
    const int ty = tid >> 4, tx = tid & 15;
    float acc[4][4] = {};
    for (int k0 = 0; k0 < K; k0 += 16) {
        {
            int r = tid >> 2, kq = tid & 3;
            float4 a4 = *reinterpret_cast<const float4*>(&A[(size_t)(row0 + r) * lda + k0 + kq * 4]);
            As[kq * 4 + 0][r] = a4.x; As[kq * 4 + 1][r] = a4.y;
            As[kq * 4 + 2][r] = a4.z; As[kq * 4 + 3][r] = a4.w;
        }
        {
            int kk = tid >> 4, cq = tid & 15;
            int col = col0 + cq * 4;
            float4 b4 = make_float4(0.f, 0.f, 0.f, 0.f);
            if (col < N) b4 = *reinterpret_cast<const float4*>(&B[(size_t)(k0 + kk) * ldb + col]);
            *reinterpret_cast<float4*>(&Bs[kk][cq * 4]) = b4;
        }
        __syncthreads();
        #pragma unroll
        for (int kk = 0; kk < 16; ++kk) {
            float4 a4 = *reinterpret_cast<const float4*>(&As[kk][ty * 4]);
            float4 b4 = *reinterpret_cast<const float4*>(&Bs[kk][tx * 4]);
            float av[4] = {a4.x, a4.y, a4.z, a4.w};
            float bv[4] = {b4.x, b4.y, b4.z, b4.w};
            #pragma unroll
            for (int i = 0; i < 4; ++i)
                #pragma unroll
                for (int j = 0; j < 4; ++j)
                    acc[i][j] = fmaf(av[i], bv[j], acc[i][j]);
        }
        __syncthreads();
    }
    #pragma unroll
    for (int i = 0; i < 4; ++i) {
        int row = row0 + ty * 4 + i;
        #pragma unroll
        for (int j = 0; j < 4; ++j) {
            int col = col0 + tx * 4 + j;
            if (col >= N) continue;
            float v = acc[i][j];
            if (EPI == 0) {
                C[(size_t)row * ldc + col] = v;
            } else if (EPI == 1) {
                C[(size_t)row * ldc + col] = fmaxf(v, 0.f);
            } else if (EPI == 2) {
                C[(size_t)row * ldc + col] = fmaxf(v, 0.f) * 0.9f + 0.1f * aux[(size_t)row * ldc + col];
            } else if (EPI == 3) {
                int b = row & 2047, l = row >> 11;
                C[(size_t)((b << 3) + l) * 256 + col] = fmaxf(v, 0.f);
                if (l == 7) aux2[(size_t)b * 256 + col] = v;
            }
        }
    }
}

// split-K (4-way) fp32 matmul into private partial buffers (deterministic).
__global__ __launch_bounds__(256) void mm_f32_splitk(
    const float* __restrict__ A, int lda,
    const float* __restrict__ B, int ldb,
    float* __restrict__ psum, int M, int N, int K)
{
    __shared__ float As[16][68];
    __shared__ float Bs[16][64];
    const int tid = threadIdx.x;
    const int row0 = blockIdx.y * 64, col0 = blockIdx.x * 64;
    const int kz = blockIdx.z;
    const int kper = K >> 2;
    const int kstart = kz * kper;
    const int ty = tid >> 4, tx = tid & 15;
    float acc[4][4] = {};
    for (int k0 = kstart; k0 < kstart + kper; k0 += 16) {
        {
            int r = tid >> 2, kq = tid & 3;
            float4 a4 = *reinterpret_cast<const float4*>(&A[(size_t)(row0 + r) * lda + k0 + kq * 4]);
            As[kq * 4 + 0][r] = a4.x; As[kq * 4 + 1][r] = a4.y;
            As[kq * 4 + 2][r] = a4.z; As[kq * 4 + 3][r] = a4.w;
        }
        {
            int kk = tid >> 4, cq = tid & 15;
            float4 b4 = *reinterpret_cast<const float4*>(&B[(size_t)(k0 + kk) * ldb + col0 + cq * 4]);
            *reinterpret_cast<float4*>(&Bs[kk][cq * 4]) = b4;
        }
        __syncthreads();
        #pragma unroll
        for (int kk = 0; kk < 16; ++kk) {
            float4 a4 = *reinterpret_cast<const float4*>(&As[kk][ty * 4]);
            float4 b4 = *reinterpret_cast<const float4*>(&Bs[kk][tx * 4]);
            float av[4] = {a4.x, a4.y, a4.z, a4.w};
            float bv[4] = {b4.x, b4.y, b4.z, b4.w};
            #pragma unroll
            for (int i = 0; i < 4; ++i)
                #pragma unroll
                for (int j = 0; j < 4; ++j)
                    acc[i][j] = fmaf(av[i], bv[j], acc[i][j]);
        }
        __syncthreads();
    }
    float* Cp = psum + (size_t)kz * M * N;
    #pragma unroll
    for (int i = 0; i < 4; ++i) {
        int row = row0 + ty * 4 + i;
        #pragma unroll
        for (int j = 0; j < 4; ++j) {
            int col = col0 + tx * 4 + j;
            Cp[(size_t)row * N + col] = acc[i][j];
        }
    }
}

__global__ __launch_bounds__(256) void k_gcn_combine(
    const float* __restrict__ psum, const float* __restrict__ xb, float* __restrict__ outp)
{
    int i = blockIdx.x * 256 + threadIdx.x;
    float s = psum[i] + psum[524288 + i] + psum[2 * 524288 + i] + psum[3 * 524288 + i];
    outp[i] = 0.95f * s + 0.05f * xb[i];
}

__global__ __launch_bounds__(256) void k_dtda(
    const float* __restrict__ Z, const float* __restrict__ bias,
    const float* __restrict__ A_log, float* __restrict__ dt, float* __restrict__ dA)
{
    int idx = blockIdx.x * 256 + threadIdx.x;
    if (idx >= 2048 * 32) return;
    int t = idx >> 5, h = idx & 31;
    float v = Z[(size_t)t * 560 + 528 + h] + bias[h];
    float dtv = softplus_f(v);
    float Ah = -expf(A_log[h]);
    dt[idx] = dtv;
    dA[idx] = expf(dtv * Ah);
}

__global__ __launch_bounds__(320) void k_conv(
    const float* __restrict__ Z, const float* __restrict__ w, const float* __restrict__ bconv,
    float* __restrict__ xhf, float* __restrict__ Bf, float* __restrict__ Cf,
    float* __restrict__ xhr, float* __restrict__ Br, float* __restrict__ Cr)
{
    int bx = blockIdx.x;               // 0..4095
    int dir = bx >> 11, t = bx & 2047;
    int c = threadIdx.x;
    if (c >= 272) return;
    float acc = bconv[c];
    #pragma unroll
    for (int k = 0; k < 4; ++k) {
        int tt = dir ? (t + 3 - k) : (t - 3 + k);
        if (tt >= 0 && tt < 2048) acc = fmaf(w[c * 4 + k], Z[(size_t)tt * 560 + 256 + c], acc);
    }
    float v = silu_f(acc);
    float* xh = dir ? xhr : xhf;
    float* B  = dir ? Br  : Bf;
    float* C  = dir ? Cr  : Cf;
    if (c < 256)       xh[(size_t)t * 256 + c] = v;
    else if (c < 264)  B[(size_t)t * 8 + (c - 256)] = v;
    else               C[(size_t)t * 8 + (c - 264)] = v;
}

// ---------------------------------------------------------------------------
// Chunk-parallel Mamba2 scan.  Virtual time j (reversed for dir=1) split into
// 32 chunks of 64.  Phase 1: local scans + cumprods + chunk summaries.
// Phase 2: 32-step serial scan over chunk summaries -> chunk-start states.
// Phase 3 (in k_gate): y_t += P_t * (s_start . C_t).
// ---------------------------------------------------------------------------
__global__ __launch_bounds__(64) void k_scan_m2_p1(
    const float* __restrict__ dt, const float* __restrict__ dA,
    const float* __restrict__ xhf, const float* __restrict__ Bf, const float* __restrict__ Cf,
    const float* __restrict__ xhr, const float* __restrict__ Br, const float* __restrict__ Cr,
    const float* __restrict__ Dvec,
    float* __restrict__ yf, float* __restrict__ yr,
    float* __restrict__ Ptbuf,   // [2][2048][32]
    float* __restrict__ Acbuf,   // [64][32]
    float* __restrict__ Sloc)    // [64][32][64]
{
    int bid = blockIdx.x;        // 0..2047
    int c  = bid & 31;
    int hh = bid >> 5;           // dir*32+h
    int dir = hh >> 5, h = hh & 31;
    const float* xhp = dir ? xhr : xhf;
    const float* Bp  = dir ? Br  : Bf;
    const float* Cp  = dir ? Cr  : Cf;
    float* yp        = dir ? yr  : yf;
    int lane = threadIdx.x;
    int p = lane >> 3, n = lane & 7;
    float Dh = Dvec[h];
    __shared__ float dAs[64];
    __shared__ float Ps[64][8];
    __shared__ float Bs[64][8];
    __shared__ float Cs[64][8];
    __shared__ float Ys[64][8];
    __shared__ float Pts[64];
    const int j0 = c * 64;
    {
        int j = j0 + lane;
        int t = dir ? (2047 - j) : j;
        dAs[lane] = dA[(size_t)t * 32 + h];
    }
    #pragma unroll
    for (int q = 0; q < 8; ++q) {
        int idx = q * 64 + lane;
        int i = idx >> 3, e = idx & 7;
        int j = j0 + i;
        int t = dir ? (2047 - j) : j;
        Ps[i][e] = dt[(size_t)t * 32 + h] * xhp[(size_t)t * 256 + h * 8 + e];
        Bs[i][e] = Bp[(size_t)t * 8 + e];
        Cs[i][e] = Cp[(size_t)t * 8 + e];
    }
    __syncthreads();
    float s = 0.f;
    float P = 1.f;
    for (int i = 0; i < 64; ++i) {
        float a = dAs[i];
        float u = Ps[i][p] * Bs[i][n];
        s = fmaf(a, s, u);
        P *= a;
        float yv = s * Cs[i][n];
        yv += __shfl_xor(yv, 1);
        yv += __shfl_xor(yv, 2);
        yv += __shfl_xor(yv, 4);
        if (n == 0) Ys[i][p] = yv;
        if (lane == 0) Pts[i] = P;
    }
    __syncthreads();
    #pragma unroll
    for (int q = 0; q < 8; ++q) {
        int idx = q * 64 + lane;
        int i = idx >> 3, e = idx & 7;
        int j = j0 + i;
        int t = dir ? (2047 - j) : j;
        yp[(size_t)t * 256 + h * 8 + e] = Ys[i][e] + xhp[(size_t)t * 256 + h * 8 + e] * Dh;
    }
    {
        int j = j0 + lane;
        Ptbuf[((size_t)dir * 2048 + j) * 32 + h] = Pts[lane];
    }
    if (lane == 0) Acbuf[hh * 32 + c] = P;
    Sloc[((size_t)hh * 32 + c) * 64 + lane] = s;
}

__global__ __launch_bounds__(64) void k_scan_m2_p2(
    const float* __restrict__ Acbuf, const float* __restrict__ Sloc,
    float* __restrict__ Sstart)  // [64][32][64]
{
    int hh = blockIdx.x;
    int lane = threadIdx.x;
    float s = 0.f;
    for (int c = 0; c < 32; ++c) {
        Sstart[((size_t)hh * 32 + c) * 64 + lane] = s;
        float a = Acbuf[hh * 32 + c];
        s = fmaf(a, s, Sloc[((size_t)hh * 32 + c) * 64 + lane]);
    }
}

// gating + per-direction RMS norm (with scan chunk correction folded in)
__global__ __launch_bounds__(256) void k_gate(
    const float* __restrict__ Z, const float* __restrict__ yf, const float* __restrict__ yr,
    const float* __restrict__ Cf, const float* __restrict__ Cr,
    const float* __restrict__ Ptbuf, const float* __restrict__ Sstart,
    const float* __restrict__ nw, float* __restrict__ gsum)
{
    int t = blockIdx.x, d = threadIdx.x;
    int h = d >> 3, p = d & 7;
    __shared__ float Csh[2][8];
    if (d < 8)       Csh[0][d] = Cf[(size_t)t * 8 + d];
    else if (d < 16) Csh[1][d - 8] = Cr[(size_t)t * 8 + (d - 8)];
    __syncthreads();
    int jf = t, jr = 2047 - t;
    int cf = jf >> 6, cr = jr >> 6;
    float Ptf = Ptbuf[((size_t)jf) * 32 + h];
    float Ptr = Ptbuf[((size_t)2048 + jr) * 32 + h];
    const float* ssf = &Sstart[(((size_t)h) * 32 + cf) * 64 + p * 8];
    const float* ssr = &Sstart[(((size_t)(32 + h)) * 32 + cr) * 64 + p * 8];
    float dotf = 0.f, dotr = 0.f;
    #pragma unroll
    for (int n2 = 0; n2 < 8; ++n2) {
        dotf = fmaf(ssf[n2], Csh[0][n2], dotf);
        dotr = fmaf(ssr[n2], Csh[1][n2], dotr);
    }
    float yfv = yf[(size_t)t * 256 + d] + Ptf * dotf;
    float yrv = yr[(size_t)t * 256 + d] + Ptr * dotr;
    float zv = Z[(size_t)t * 560 + d];
    float sz = silu_f(zv);
    float gf = yfv * sz;
    float gr = yrv * sz;
    float vf = gf * gf, vr = gr * gr;
    for (int o = 32; o > 0; o >>= 1) { vf += __shfl_down(vf, o); vr += __shfl_down(vr, o); }
    __shared__ float sfa[4], sra[4];
    __shared__ float tot[2];
    int wid = d >> 6;
    if ((d & 63) == 0) { sfa[wid] = vf; sra[wid] = vr; }
    __syncthreads();
    if (d == 0) {
        tot[0] = sfa[0] + sfa[1] + sfa[2] + sfa[3];
        tot[1] = sra[0] + sra[1] + sra[2] + sra[3];
    }
    __syncthreads();
    float inf_ = rsqrtf(tot[0] / 256.f + 1e-5f);
    float inr_ = rsqrtf(tot[1] / 256.f + 1e-5f);
    gsum[(size_t)t * 256 + d] = (gf * inf_ + gr * inr_) * nw[d];
}

__global__ __launch_bounds__(256) void k_xb(
    const float* __restrict__ X, const float* __restrict__ g, const float* __restrict__ b,
    float* __restrict__ outp)
{
    int i = blockIdx.x * 256 + threadIdx.x;
    int d = i & 255;
    const float sc = 0.99999500003749951f;  // 1/sqrt(1+1e-5)
    float v = X[i] * (g[d] * sc) + b[d];
    outp[i] = fmaxf(v, 0.f);
}

__global__ __launch_bounds__(256) void k_scan_gcn(
    const float* __restrict__ xdbl,   // [16384][48] (relu'd)
    const float* __restrict__ dtW,    // [16][256]
    const float* __restrict__ A_log,  // [256][16]
    const float* __restrict__ Dv,     // [256]
    float* __restrict__ feats)        // [8][2048][256], overwritten with y
{
    int b = blockIdx.x, d = threadIdx.x;
    __shared__ float xrow[8][48];
    for (int j = d; j < 384; j += 256) {
        int l = j / 48, k = j % 48;
        xrow[l][k] = xdbl[(size_t)(l * 2048 + b) * 48 + k];
    }
    __syncthreads();
    float a[16];
    #pragma unroll
    for (int n = 0; n < 16; ++n) a[n] = -expf(A_log[d * 16 + n]);
    float Dd = Dv[d];
    float s[16];
    #pragma unroll
    for (int n = 0; n < 16; ++n) s[n] = 0.f;
    for (int l = 0; l < 8; ++l) {
        float accd = 0.f;
        #pragma unroll
        for (int k = 0; k < 16; ++k) accd = fmaf(xrow[l][k], dtW[k * 256 + d], accd);
        float dl = softplus_f(accd);
        size_t r = (size_t)(l * 2048 + b) * 256 + d;
        float xv = feats[r];
        float du = dl * xv;
        float y = 0.f;
        #pragma unroll
        for (int n = 0; n < 16; ++n) {
            float dAn = expf(dl * a[n]);
            s[n] = fmaf(dAn, s[n], du * xrow[l][16 + n]);
            y = fmaf(s[n], xrow[l][32 + n], y);
        }
        feats[r] = y + xv * Dd;
    }
}

__global__ __launch_bounds__(256) void k_head(
    const float* __restrict__ lastl, const float* __restrict__ X, const float* __restrict__ gout,
    const float* __restrict__ g2, const float* __restrict__ b2, const float* __restrict__ W2,
    float* __restrict__ out1)
{
    int b = blockIdx.x, d = threadIdx.x;
    __shared__ float ov[256];
    __shared__ float yv[40];
    const float sc = 0.99999500003749951f;
    float v = (lastl[(size_t)b * 256 + d] + X[(size_t)b * 256 + d]) * 0.5f
              + gout[(size_t)b * 256 + d] * 0.5f;
    v = v * (g2[d] * sc) + b2[d];
    ov[d] = fmaxf(v, 0.f);
    __syncthreads();
    if (d < 40) {
        float acc = 0.f;
        for (int k = 0; k < 256; ++k) acc = fmaf(ov[k], W2[k * 40 + d], acc);
        yv[d] = acc;
    }
    __syncthreads();
    if (d < 40) {
        float m = -1e30f;
        for (int j = 0; j < 40; ++j) m = fmaxf(m, yv[j]);
        float se = 0.f;
        for (int j = 0; j < 40; ++j) se += expf(yv[j] - m);
        out1[(size_t)b * 40 + d] = yv[d] - m - logf(se);
    }
}

// ---------------------------------------------------------------------------
extern "C" void kernel_launch(void* const* d_in, const int* in_sizes, int n_in,
                              void* d_out, int out_size, void* d_ws, size_t ws_size,
                              hipStream_t stream)
{
    const float* x      = (const float*)d_in[0];
    const float* adj    = (const float*)d_in[1];
    const float* lin1W  = (const float*)d_in[2];
    const float* inproj = (const float*)d_in[3];
    const float* convw  = (const float*)d_in[4];
    const float* convb  = (const float*)d_in[5];
    const float* dtbias = (const float*)d_in[6];
    const float* m2Alog = (const float*)d_in[7];
    const float* m2D    = (const float*)d_in[8];
    const float* normw  = (const float*)d_in[9];
    const float* outprj = (const float*)d_in[10];
    const float* xprojW = (const float*)d_in[11];
    const float* dtprjW = (const float*)d_in[12];
    const float* bAlog  = (const float*)d_in[13];
    const float* bD     = (const float*)d_in[14];
    const float* boutW  = (const float*)d_in[15];
    const float* bn1g   = (const float*)d_in[16];
    const float* bn1b   = (const float*)d_in[17];
    const float* bn2g   = (const float*)d_in[18];
    const float* bn2b   = (const float*)d_in[19];
    const float* lin2W  = (const float*)d_in[20];
    float* out = (float*)d_out;
    float* ws  = (float*)d_ws;

    float* X     = ws + 0;         // 2048*256
    float* Z     = ws + 524288;    // 2048*560
    float* dt    = ws + 1671168;   // 2048*32
    float* dA    = ws + 1736704;   // 2048*32
    float* xhf   = ws + 1802240;   // 2048*256
    float* Bf    = ws + 2326528;   // 2048*8
    float* Cf    = ws + 2342912;   // 2048*8
    float* xhr   = ws + 2359296;   // 2048*256
    float* Br    = ws + 2883584;   // 2048*8
    float* Cr    = ws + 2899968;   // 2048*8
    float* yf    = ws + 2916352;   // 2048*256
    float* yr    = ws + 3440640;   // 2048*256
    float* gsum  = ws + 3964928;   // 2048*256
    float* gout  = ws + 4489216;   // 2048*256
    float* feats = ws + 5013504;   // 8*2048*256
    float* xdbl  = ws + 9207808;   // 16384*48
    float* lastl = ws + 9994240;   // 2048*256
    float* psum  = ws + 10518528;  // 4*2048*256
    // scan scratch aliases psum (psum not live until GCN chain, in-order stream)
    float* Ptbuf  = psum;               // 2*2048*32 = 131072
    float* Acbuf  = psum + 131072;      // 2048
    float* Sloc   = psum + 133120;      // 131072
    float* Sstart = psum + 264192;      // 131072
    (void)ws_size; (void)in_sizes; (void)n_in; (void)out_size;

    dim3 blk(256);
    // 1. X = x @ lin1_W        (2048x512 @ 512x256)
    mm_f32<0><<<dim3(4, 32), blk, 0, stream>>>(x, 512, lin1W, 256, X, 256, 2048, 256, 512, nullptr, nullptr);
    // 2. Z = X @ in_proj       (2048x256 @ 256x560)
    mm_f32<0><<<dim3(9, 32), blk, 0, stream>>>(X, 256, inproj, 560, Z, 560, 2048, 560, 256, nullptr, nullptr);
    // 3. dt / dA
    k_dtda<<<dim3(256), blk, 0, stream>>>(Z, dtbias, m2Alog, dt, dA);
    // 4. conv (both directions)
    k_conv<<<dim3(4096), dim3(320), 0, stream>>>(Z, convw, convb, xhf, Bf, Cf, xhr, Br, Cr);
    // 5. chunk-parallel bidirectional selective scan
    k_scan_m2_p1<<<dim3(2048), dim3(64), 0, stream>>>(dt, dA, xhf, Bf, Cf, xhr, Br, Cr, m2D,
                                                      yf, yr, Ptbuf, Acbuf, Sloc);
    k_scan_m2_p2<<<dim3(64), dim3(64), 0, stream>>>(Acbuf, Sloc, Sstart);
    // 6. gate + RMS (both dirs, + chunk correction) -> gsum
    k_gate<<<dim3(2048), blk, 0, stream>>>(Z, yf, yr, Cf, Cr, Ptbuf, Sstart, normw, gsum);
    // 7. gout = relu(gsum@out_proj)*0.9 + 0.1*X
    mm_f32<2><<<dim3(4, 32), blk, 0, stream>>>(gsum, 256, outprj, 256, gout, 256, 2048, 256, 256, X, nullptr);
    // 8. feats[0] = xb = relu(bn1(X))
    k_xb<<<dim3(2048), blk, 0, stream>>>(X, bn1g, bn1b, feats);
    // 9. GCN chain: feats[i] = 0.95*(adj@feats[i-1]) + 0.05*feats[0]
    for (int i = 1; i < 8; ++i) {
        mm_f32_splitk<<<dim3(4, 32, 4), blk, 0, stream>>>(adj, 2048, feats + (size_t)(i - 1) * 524288, 256,
                                                          psum, 2048, 256, 2048);
        k_gcn_combine<<<dim3(2048), blk, 0, stream>>>(psum, feats, feats + (size_t)i * 524288);
    }
    // 10. xdbl = relu(feats @ xproj_W)   (16384x256 @ 256x48)
    mm_f32<1><<<dim3(1, 256), blk, 0, stream>>>(feats, 256, xprojW, 48, xdbl, 48, 16384, 48, 256, nullptr, nullptr);
    // 11. GCN scan (delta proj inlined), y written in-place over feats
    k_scan_gcn<<<dim3(2048), blk, 0, stream>>>(xdbl, dtprjW, bAlog, bD, feats);
    // 12. all_out = relu(y @ outproj_W) remapped (b,l,d); raw l=7 -> lastl
    mm_f32<3><<<dim3(4, 256), blk, 0, stream>>>(feats, 256, boutW, 256, out, 256, 16384, 256, 256, nullptr, lastl);
    // 13. head: mix + bn2 + relu + lin2 + log_softmax
    k_head<<<dim3(2048), blk, 0, stream>>>(lastl, X, gout, bn2g, bn2b, lin2W, out + 4194304);
}

// Round 5
// 305.236 us; speedup vs baseline: 2.8430x; 1.7406x over previous
//
#include <hip/hip_runtime.h>
#include <math.h>

// ---------------------------------------------------------------------------
// GCN_mamba_Net: chunk-parallel Mamba2 scan + fp16-MFMA GCN chain.
// N=2048, F_IN=512, D_MODEL=D_INNER=256, NHEADS=32, HDIM=8, D_ST2=8,
// CONV_DIM=272, LAYERS=8, DT_RANK=16, N_STATE=16, NUM_CLASSES=40.
// ---------------------------------------------------------------------------

typedef _Float16 half8 __attribute__((ext_vector_type(8)));
typedef _Float16 half4v __attribute__((ext_vector_type(4)));
typedef float f32x4 __attribute__((ext_vector_type(4)));

__device__ __forceinline__ float softplus_fast(float x) {
    return fmaxf(x, 0.f) + __logf(1.f + __expf(-fabsf(x)));
}
__device__ __forceinline__ float silu_fast(float x) {
    return __fdividef(x, 1.f + __expf(-x));
}

// ---------------------------------------------------------------------------
// fp32 matmul (small projections): C[M,N]=A@B, 64x64 tile, BK=16.
// EPI: 0 none, 1 relu, 2 gout (relu*0.9+0.1*aux).
// ---------------------------------------------------------------------------
template<int EPI>
__global__ __launch_bounds__(256) void mm_f32(
    const float* __restrict__ A, int lda,
    const float* __restrict__ B, int ldb,
    float* __restrict__ C, int ldc,
    int M, int N, int K,
    const float* __restrict__ aux)
{
    __shared__ float As[16][68];
    __shared__ float Bs[16][64];
    const int tid = threadIdx.x;
    const int row0 = blockIdx.y * 64, col0 = blockIdx.x * 64;
    const int ty = tid >> 4, tx = tid & 15;
    float acc[4][4] = {};
    for (int k0 = 0; k0 < K; k0 += 16) {
        {
            int r = tid >> 2, kq = tid & 3;
            float4 a4 = *reinterpret_cast<const float4*>(&A[(size_t)(row0 + r) * lda + k0 + kq * 4]);
            As[kq * 4 + 0][r] = a4.x; As[kq * 4 + 1][r] = a4.y;
            As[kq * 4 + 2][r] = a4.z; As[kq * 4 + 3][r] = a4.w;
        }
        {
            int kk = tid >> 4, cq = tid & 15;
            int col = col0 + cq * 4;
            float4 b4 = make_float4(0.f, 0.f, 0.f, 0.f);
            if (col < N) b4 = *reinterpret_cast<const float4*>(&B[(size_t)(k0 + kk) * ldb + col]);
            *reinterpret_cast<float4*>(&Bs[kk][cq * 4]) = b4;
        }
        __syncthreads();
        #pragma unroll
        for (int kk = 0; kk < 16; ++kk) {
            float4 a4 = *reinterpret_cast<const float4*>(&As[kk][ty * 4]);
            float4 b4 = *reinterpret_cast<const float4*>(&Bs[kk][tx * 4]);
            float av[4] = {a4.x, a4.y, a4.z, a4.w};
            float bv[4] = {b4.x, b4.y, b4.z, b4.w};
            #pragma unroll
            for (int i = 0; i < 4; ++i)
                #pragma unroll
                for (int j = 0; j < 4; ++j)
                    acc[i][j] = fmaf(av[i], bv[j], acc[i][j]);
        }
        __syncthreads();
    }
    #pragma unroll
    for (int i = 0; i < 4; ++i) {
        int row = row0 + ty * 4 + i;
        #pragma unroll
        for (int j = 0; j < 4; ++j) {
            int col = col0 + tx * 4 + j;
            if (col >= N) continue;
            float v = acc[i][j];
            if (EPI == 0) {
                C[(size_t)row * ldc + col] = v;
            } else if (EPI == 1) {
                C[(size_t)row * ldc + col] = fmaxf(v, 0.f);
            } else {
                C[(size_t)row * ldc + col] = fmaxf(v, 0.f) * 0.9f + 0.1f * aux[(size_t)row * ldc + col];
            }
        }
    }
}

// ---------------------------------------------------------------------------
// fp16 MFMA matmul: C[M,N] = A16[M,K](lda) @ BT16[N,K](ldb)^T.
// 256 thr = 4 waves; block tile 128(m) x 64(n); BK=32; 16x16x32 f16 MFMA.
// grid: (N/64, M/128, KSPLIT).  kchunk = K/KSPLIT (multiple of 32).
// EPI 0: psum[kz][M][256] partial write.   EPI 3: all_out remap + lastl.
// LDS staging: A tile 128x32 halves -> 16 halves/thread (2x float4);
//              B tile 64x32 halves  ->  8 halves/thread (1x float4).
// ---------------------------------------------------------------------------
template<int EPI>
__global__ __launch_bounds__(256) void mm16(
    const _Float16* __restrict__ A16, int lda,
    const _Float16* __restrict__ BT16, int ldb,
    float* __restrict__ dst, float* __restrict__ aux, int kchunk)
{
    __shared__ _Float16 As[128][48];   // pad 48: 96B row stride, 16B-aligned
    __shared__ _Float16 Bs[64][48];
    const int tid = threadIdx.x;
    const int col0 = blockIdx.x * 64;
    const int row0 = blockIdx.y * 128;
    const int kz = blockIdx.z;
    const int k0 = kz * kchunk;
    const int wave = tid >> 6, lane = tid & 63;
    f32x4 acc[2][4];
    #pragma unroll
    for (int i = 0; i < 2; ++i)
        #pragma unroll
        for (int j = 0; j < 4; ++j)
            acc[i][j] = (f32x4){0.f, 0.f, 0.f, 0.f};
    const int ar = tid >> 1, ac = (tid & 1) * 16;   // A: 2 thr/row, 16 halves each
    const int br = tid >> 2, bc = (tid & 3) * 8;    // B: 4 thr/row, 8 halves each
    const int lrow = lane & 15, kof = (lane >> 4) * 8;
    for (int ks = 0; ks < kchunk; ks += 32) {
        {
            const _Float16* src = A16 + (size_t)(row0 + ar) * lda + k0 + ks + ac;
            *reinterpret_cast<float4*>(&As[ar][ac])     = *reinterpret_cast<const float4*>(src);
            *reinterpret_cast<float4*>(&As[ar][ac + 8]) = *reinterpret_cast<const float4*>(src + 8);
        }
        {
            const _Float16* src = BT16 + (size_t)(col0 + br) * ldb + k0 + ks + bc;
            *reinterpret_cast<float4*>(&Bs[br][bc]) = *reinterpret_cast<const float4*>(src);
        }
        __syncthreads();
        half8 a[2], b[4];
        #pragma unroll
        for (int fr = 0; fr < 2; ++fr)
            a[fr] = *reinterpret_cast<const half8*>(&As[wave * 32 + fr * 16 + lrow][kof]);
        #pragma unroll
        for (int fc = 0; fc < 4; ++fc)
            b[fc] = *reinterpret_cast<const half8*>(&Bs[fc * 16 + lrow][kof]);
        #pragma unroll
        for (int fr = 0; fr < 2; ++fr)
            #pragma unroll
            for (int fc = 0; fc < 4; ++fc)
                acc[fr][fc] = __builtin_amdgcn_mfma_f32_16x16x32_f16(a[fr], b[fc], acc[fr][fc], 0, 0, 0);
        __syncthreads();
    }
    const int col = lane & 15, rbase = (lane >> 4) * 4;
    if (EPI == 0) {
        float* P = dst + (size_t)kz * gridDim.y * 128 * 256;
        #pragma unroll
        for (int fr = 0; fr < 2; ++fr)
            #pragma unroll
            for (int fc = 0; fc < 4; ++fc) {
                int r0 = row0 + wave * 32 + fr * 16 + rbase;
                int c = col0 + fc * 16 + col;
                #pragma unroll
                for (int i = 0; i < 4; ++i)
                    P[(size_t)(r0 + i) * 256 + c] = acc[fr][fc][i];
            }
    } else {
        #pragma unroll
        for (int fr = 0; fr < 2; ++fr)
            #pragma unroll
            for (int fc = 0; fc < 4; ++fc) {
                int c = col0 + fc * 16 + col;
                #pragma unroll
                for (int i = 0; i < 4; ++i) {
                    int m = row0 + wave * 32 + fr * 16 + rbase + i;
                    int bb = m & 2047, ll = m >> 11;
                    float v = acc[fr][fc][i];
                    dst[(size_t)((bb << 3) + ll) * 256 + c] = fmaxf(v, 0.f);
                    if (ll == 7) aux[(size_t)bb * 256 + c] = v;
                }
            }
    }
}

// adj fp32 -> fp16, elementwise (4.19M elems, 4 per thread)
__global__ __launch_bounds__(256) void k_adj16(
    const float* __restrict__ adj, _Float16* __restrict__ o)
{
    int i = (blockIdx.x * 256 + threadIdx.x) * 4;
    float4 v = *reinterpret_cast<const float4*>(&adj[i]);
    half4v h;
    h[0] = (_Float16)v.x; h[1] = (_Float16)v.y; h[2] = (_Float16)v.z; h[3] = (_Float16)v.w;
    *reinterpret_cast<half4v*>(&o[i]) = h;
}

// boutW [256k][256n] -> WT16 [n][k]
__global__ __launch_bounds__(256) void k_w16t(
    const float* __restrict__ w, _Float16* __restrict__ o)
{
    int n = blockIdx.x, k = threadIdx.x;
    o[n * 256 + k] = (_Float16)w[k * 256 + n];
}

// xb = relu(bn1(X)); write fp32 xb + fp16 transposed fT16[n][m]
__global__ __launch_bounds__(256) void k_xb_t16(
    const float* __restrict__ X, const float* __restrict__ g, const float* __restrict__ b,
    float* __restrict__ xb, _Float16* __restrict__ fT16)
{
    const float sc = 0.99999500003749951f;  // 1/sqrt(1+1e-5)
    int m0 = (blockIdx.x >> 3) * 32, n0 = (blockIdx.x & 7) * 32;
    int tx = threadIdx.x & 31, tg = threadIdx.x >> 5;
    __shared__ float T[32][33];
    float gd = g[n0 + tx] * sc, bd = b[n0 + tx];
    #pragma unroll
    for (int i = 0; i < 4; ++i) {
        int m = tg * 4 + i;
        size_t idx = (size_t)(m0 + m) * 256 + n0 + tx;
        float v = fmaxf(X[idx] * gd + bd, 0.f);
        xb[idx] = v;
        T[m][tx] = v;
    }
    __syncthreads();
    #pragma unroll
    for (int j = 0; j < 4; ++j) {
        int n = tg * 4 + j;
        fT16[(size_t)(n0 + n) * 2048 + m0 + tx] = (_Float16)T[tx][n];
    }
}

// xi = 0.95*sum(psum[0..7]) + 0.05*xb; write fp32 xi + fp16 transposed fT16
__global__ __launch_bounds__(256) void k_combine_t16(
    const float* __restrict__ psum, const float* __restrict__ xb,
    float* __restrict__ xi, _Float16* __restrict__ fT16)
{
    int m0 = (blockIdx.x >> 3) * 32, n0 = (blockIdx.x & 7) * 32;
    int tx = threadIdx.x & 31, tg = threadIdx.x >> 5;
    __shared__ float T[32][33];
    #pragma unroll
    for (int i = 0; i < 4; ++i) {
        int m = tg * 4 + i;
        size_t idx = (size_t)(m0 + m) * 256 + n0 + tx;
        float s = psum[idx];
        #pragma unroll
        for (int q = 1; q < 8; ++q) s += psum[idx + (size_t)q * 524288];
        float v = 0.95f * s + 0.05f * xb[idx];
        xi[idx] = v;
        T[m][tx] = v;
    }
    __syncthreads();
    #pragma unroll
    for (int j = 0; j < 4; ++j) {
        int n = tg * 4 + j;
        fT16[(size_t)(n0 + n) * 2048 + m0 + tx] = (_Float16)T[tx][n];
    }
}

__global__ __launch_bounds__(256) void k_dtda(
    const float* __restrict__ Z, const float* __restrict__ bias,
    const float* __restrict__ A_log, float* __restrict__ dt, float* __restrict__ dA)
{
    int idx = blockIdx.x * 256 + threadIdx.x;
    if (idx >= 2048 * 32) return;
    int t = idx >> 5, h = idx & 31;
    float v = Z[(size_t)t * 560 + 528 + h] + bias[h];
    float dtv = softplus_fast(v);
    float Ah = -__expf(A_log[h]);
    dt[idx] = dtv;
    dA[idx] = __expf(dtv * Ah);
}

__global__ __launch_bounds__(320) void k_conv(
    const float* __restrict__ Z, const float* __restrict__ w, const float* __restrict__ bconv,
    float* __restrict__ xhf, float* __restrict__ Bf, float* __restrict__ Cf,
    float* __restrict__ xhr, float* __restrict__ Br, float* __restrict__ Cr)
{
    int bx = blockIdx.x;               // 0..4095
    int dir = bx >> 11, t = bx & 2047;
    int c = threadIdx.x;
    if (c >= 272) return;
    float acc = bconv[c];
    #pragma unroll
    for (int k = 0; k < 4; ++k) {
        int tt = dir ? (t + 3 - k) : (t - 3 + k);
        if (tt >= 0 && tt < 2048) acc = fmaf(w[c * 4 + k], Z[(size_t)tt * 560 + 256 + c], acc);
    }
    float v = silu_fast(acc);
    float* xh = dir ? xhr : xhf;
    float* B  = dir ? Br  : Bf;
    float* C  = dir ? Cr  : Cf;
    if (c < 256)       xh[(size_t)t * 256 + c] = v;
    else if (c < 264)  B[(size_t)t * 8 + (c - 256)] = v;
    else               C[(size_t)t * 8 + (c - 264)] = v;
}

// ---------------------------------------------------------------------------
// Chunk-parallel Mamba2 scan (32 chunks of 64 virtual steps).
// ---------------------------------------------------------------------------
__global__ __launch_bounds__(64) void k_scan_m2_p1(
    const float* __restrict__ dt, const float* __restrict__ dA,
    const float* __restrict__ xhf, const float* __restrict__ Bf, const float* __restrict__ Cf,
    const float* __restrict__ xhr, const float* __restrict__ Br, const float* __restrict__ Cr,
    const float* __restrict__ Dvec,
    float* __restrict__ yf, float* __restrict__ yr,
    float* __restrict__ Ptbuf,   // [2][2048][32]
    float* __restrict__ Acbuf,   // [64][32]
    float* __restrict__ Sloc)    // [64][32][64]
{
    int bid = blockIdx.x;        // 0..2047
    int c  = bid & 31;
    int hh = bid >> 5;           // dir*32+h
    int dir = hh >> 5, h = hh & 31;
    const float* xhp = dir ? xhr : xhf;
    const float* Bp  = dir ? Br  : Bf;
    const float* Cp  = dir ? Cr  : Cf;
    float* yp        = dir ? yr  : yf;
    int lane = threadIdx.x;
    int p = lane >> 3, n = lane & 7;
    float Dh = Dvec[h];
    __shared__ float dAs[64];
    __shared__ float Ps[64][8];
    __shared__ float Bs[64][8];
    __shared__ float Cs[64][8];
    __shared__ float Ys[64][8];
    __shared__ float Pts[64];
    const int j0 = c * 64;
    {
        int j = j0 + lane;
        int t = dir ? (2047 - j) : j;
        dAs[lane] = dA[(size_t)t * 32 + h];
    }
    #pragma unroll
    for (int q = 0; q < 8; ++q) {
        int idx = q * 64 + lane;
        int i = idx >> 3, e = idx & 7;
        int j = j0 + i;
        int t = dir ? (2047 - j) : j;
        Ps[i][e] = dt[(size_t)t * 32 + h] * xhp[(size_t)t * 256 + h * 8 + e];
        Bs[i][e] = Bp[(size_t)t * 8 + e];
        Cs[i][e] = Cp[(size_t)t * 8 + e];
    }
    __syncthreads();
    float s = 0.f;
    float P = 1.f;
    for (int i = 0; i < 64; ++i) {
        float a = dAs[i];
        float u = Ps[i][p] * Bs[i][n];
        s = fmaf(a, s, u);
        P *= a;
        float yv = s * Cs[i][n];
        yv += __shfl_xor(yv, 1);
        yv += __shfl_xor(yv, 2);
        yv += __shfl_xor(yv, 4);
        if (n == 0) Ys[i][p] = yv;
        if (lane == 0) Pts[i] = P;
    }
    __syncthreads();
    #pragma unroll
    for (int q = 0; q < 8; ++q) {
        int idx = q * 64 + lane;
        int i = idx >> 3, e = idx & 7;
        int j = j0 + i;
        int t = dir ? (2047 - j) : j;
        yp[(size_t)t * 256 + h * 8 + e] = Ys[i][e] + xhp[(size_t)t * 256 + h * 8 + e] * Dh;
    }
    {
        int j = j0 + lane;
        Ptbuf[((size_t)dir * 2048 + j) * 32 + h] = Pts[lane];
    }
    if (lane == 0) Acbuf[hh * 32 + c] = P;
    Sloc[((size_t)hh * 32 + c) * 64 + lane] = s;
}

__global__ __launch_bounds__(64) void k_scan_m2_p2(
    const float* __restrict__ Acbuf, const float* __restrict__ Sloc,
    float* __restrict__ Sstart)
{
    int hh = blockIdx.x;
    int lane = threadIdx.x;
    float s = 0.f;
    for (int c = 0; c < 32; ++c) {
        Sstart[((size_t)hh * 32 + c) * 64 + lane] = s;
        float a = Acbuf[hh * 32 + c];
        s = fmaf(a, s, Sloc[((size_t)hh * 32 + c) * 64 + lane]);
    }
}

// gating + per-direction RMS norm (with scan chunk correction folded in)
__global__ __launch_bounds__(256) void k_gate(
    const float* __restrict__ Z, const float* __restrict__ yf, const float* __restrict__ yr,
    const float* __restrict__ Cf, const float* __restrict__ Cr,
    const float* __restrict__ Ptbuf, const float* __restrict__ Sstart,
    const float* __restrict__ nw, float* __restrict__ gsum)
{
    int t = blockIdx.x, d = threadIdx.x;
    int h = d >> 3, p = d & 7;
    __shared__ float Csh[2][8];
    if (d < 8)       Csh[0][d] = Cf[(size_t)t * 8 + d];
    else if (d < 16) Csh[1][d - 8] = Cr[(size_t)t * 8 + (d - 8)];
    __syncthreads();
    int jf = t, jr = 2047 - t;
    int cf = jf >> 6, cr = jr >> 6;
    float Ptf = Ptbuf[((size_t)jf) * 32 + h];
    float Ptr = Ptbuf[((size_t)2048 + jr) * 32 + h];
    const float* ssf = &Sstart[(((size_t)h) * 32 + cf) * 64 + p * 8];
    const float* ssr = &Sstart[(((size_t)(32 + h)) * 32 + cr) * 64 + p * 8];
    float dotf = 0.f, dotr = 0.f;
    #pragma unroll
    for (int n2 = 0; n2 < 8; ++n2) {
        dotf = fmaf(ssf[n2], Csh[0][n2], dotf);
        dotr = fmaf(ssr[n2], Csh[1][n2], dotr);
    }
    float yfv = yf[(size_t)t * 256 + d] + Ptf * dotf;
    float yrv = yr[(size_t)t * 256 + d] + Ptr * dotr;
    float zv = Z[(size_t)t * 560 + d];
    float sz = silu_fast(zv);
    float gf = yfv * sz;
    float gr = yrv * sz;
    float vf = gf * gf, vr = gr * gr;
    for (int o = 32; o > 0; o >>= 1) { vf += __shfl_down(vf, o); vr += __shfl_down(vr, o); }
    __shared__ float sfa[4], sra[4];
    __shared__ float tot[2];
    int wid = d >> 6;
    if ((d & 63) == 0) { sfa[wid] = vf; sra[wid] = vr; }
    __syncthreads();
    if (d == 0) {
        tot[0] = sfa[0] + sfa[1] + sfa[2] + sfa[3];
        tot[1] = sra[0] + sra[1] + sra[2] + sra[3];
    }
    __syncthreads();
    float inf_ = rsqrtf(tot[0] / 256.f + 1e-5f);
    float inr_ = rsqrtf(tot[1] / 256.f + 1e-5f);
    gsum[(size_t)t * 256 + d] = (gf * inf_ + gr * inr_) * nw[d];
}

// GCN-mamba scan; fast transcendentals; emits fp32 y (in-place) + fp16 mirror.
__global__ __launch_bounds__(256) void k_scan_gcn(
    const float* __restrict__ xdbl,   // [16384][48]
    const float* __restrict__ dtW,    // [16][256]
    const float* __restrict__ A_log,  // [256][16]
    const float* __restrict__ Dv,     // [256]
    float* __restrict__ feats,        // [8][2048][256] in/out
    _Float16* __restrict__ f16o)      // [16384][256] fp16 mirror of y
{
    int b = blockIdx.x, d = threadIdx.x;
    __shared__ float xrow[8][48];
    for (int j = d; j < 384; j += 256) {
        int l = j / 48, k = j % 48;
        xrow[l][k] = xdbl[(size_t)(l * 2048 + b) * 48 + k];
    }
    __syncthreads();
    float a[16];
    #pragma unroll
    for (int n = 0; n < 16; ++n) a[n] = -__expf(A_log[d * 16 + n]);
    float Dd = Dv[d];
    float s[16];
    #pragma unroll
    for (int n = 0; n < 16; ++n) s[n] = 0.f;
    for (int l = 0; l < 8; ++l) {
        float accd = 0.f;
        #pragma unroll
        for (int k = 0; k < 16; ++k) accd = fmaf(xrow[l][k], dtW[k * 256 + d], accd);
        float dl = softplus_fast(accd);
        size_t r = (size_t)(l * 2048 + b) * 256 + d;
        float xv = feats[r];
        float du = dl * xv;
        float y = 0.f;
        #pragma unroll
        for (int n = 0; n < 16; ++n) {
            float dAn = __expf(dl * a[n]);
            s[n] = fmaf(dAn, s[n], du * xrow[l][16 + n]);
            y = fmaf(s[n], xrow[l][32 + n], y);
        }
        float res = y + xv * Dd;
        feats[r] = res;
        f16o[r] = (_Float16)res;
    }
}

__global__ __launch_bounds__(256) void k_head(
    const float* __restrict__ lastl, const float* __restrict__ X, const float* __restrict__ gout,
    const float* __restrict__ g2, const float* __restrict__ b2, const float* __restrict__ W2,
    float* __restrict__ out1)
{
    int b = blockIdx.x, d = threadIdx.x;
    __shared__ float ov[256];
    __shared__ float yv[40];
    const float sc = 0.99999500003749951f;
    float v = (lastl[(size_t)b * 256 + d] + X[(size_t)b * 256 + d]) * 0.5f
              + gout[(size_t)b * 256 + d] * 0.5f;
    v = v * (g2[d] * sc) + b2[d];
    ov[d] = fmaxf(v, 0.f);
    __syncthreads();
    if (d < 40) {
        float acc = 0.f;
        for (int k = 0; k < 256; ++k) acc = fmaf(ov[k], W2[k * 40 + d], acc);
        yv[d] = acc;
    }
    __syncthreads();
    if (d < 40) {
        float m = -1e30f;
        for (int j = 0; j < 40; ++j) m = fmaxf(m, yv[j]);
        float se = 0.f;
        for (int j = 0; j < 40; ++j) se += expf(yv[j] - m);
        out1[(size_t)b * 40 + d] = yv[d] - m - logf(se);
    }
}

// ---------------------------------------------------------------------------
extern "C" void kernel_launch(void* const* d_in, const int* in_sizes, int n_in,
                              void* d_out, int out_size, void* d_ws, size_t ws_size,
                              hipStream_t stream)
{
    const float* x      = (const float*)d_in[0];
    const float* adj    = (const float*)d_in[1];
    const float* lin1W  = (const float*)d_in[2];
    const float* inproj = (const float*)d_in[3];
    const float* convw  = (const float*)d_in[4];
    const float* convb  = (const float*)d_in[5];
    const float* dtbias = (const float*)d_in[6];
    const float* m2Alog = (const float*)d_in[7];
    const float* m2D    = (const float*)d_in[8];
    const float* normw  = (const float*)d_in[9];
    const float* outprj = (const float*)d_in[10];
    const float* xprojW = (const float*)d_in[11];
    const float* dtprjW = (const float*)d_in[12];
    const float* bAlog  = (const float*)d_in[13];
    const float* bD     = (const float*)d_in[14];
    const float* boutW  = (const float*)d_in[15];
    const float* bn1g   = (const float*)d_in[16];
    const float* bn1b   = (const float*)d_in[17];
    const float* bn2g   = (const float*)d_in[18];
    const float* bn2b   = (const float*)d_in[19];
    const float* lin2W  = (const float*)d_in[20];
    float* out = (float*)d_out;
    float* ws  = (float*)d_ws;

    float* X     = ws + 0;         // 524288
    float* Z     = ws + 524288;    // 1146880
    float* dt    = ws + 1671168;   // 65536
    float* dA    = ws + 1736704;   // 65536
    float* xhf   = ws + 1802240;   // 524288
    float* Bf    = ws + 2326528;   // 16384
    float* Cf    = ws + 2342912;   // 16384
    float* xhr   = ws + 2359296;   // 524288
    float* Br    = ws + 2883584;   // 16384
    float* Cr    = ws + 2899968;   // 16384
    float* yf    = ws + 2916352;   // 524288
    float* yr    = ws + 3440640;   // 524288
    float* gsum  = ws + 3964928;   // 524288
    float* gout  = ws + 4489216;   // 524288
    float* feats = ws + 5013504;   // 4194304
    float* xdbl  = ws + 9207808;   // 786432
    float* lastl = ws + 9994240;   // 524288
    float* psum  = ws + 10518528;  // 8*524288 = 4194304 -> ends 14712832
    _Float16* adj16h  = (_Float16*)(ws + 14712832);  // 4.19M halves -> +2097152
    _Float16* fT16h   = (_Float16*)(ws + 16809984);  // 524288 halves -> +262144
    _Float16* WT16h   = (_Float16*)(ws + 17072128);  // 65536 halves -> +32768
    // feats16 aliases Z..Cf-end region (dead after k_gate; used from step 12 on)
    _Float16* feats16h = (_Float16*)(ws + 524288);   // 4.19M halves
    // m2-scan scratch aliases psum (dead before GCN chain)
    float* Ptbuf  = psum;               // 131072
    float* Acbuf  = psum + 131072;      // 2048
    float* Sloc   = psum + 133120;      // 131072
    float* Sstart = psum + 264192;      // 131072
    (void)ws_size; (void)in_sizes; (void)n_in; (void)out_size;

    dim3 blk(256);
    // 1. X = x @ lin1_W
    mm_f32<0><<<dim3(4, 32), blk, 0, stream>>>(x, 512, lin1W, 256, X, 256, 2048, 256, 512, nullptr);
    // 2. Z = X @ in_proj
    mm_f32<0><<<dim3(9, 32), blk, 0, stream>>>(X, 256, inproj, 560, Z, 560, 2048, 560, 256, nullptr);
    // 3. dt / dA
    k_dtda<<<dim3(256), blk, 0, stream>>>(Z, dtbias, m2Alog, dt, dA);
    // 4. conv (both directions)
    k_conv<<<dim3(4096), dim3(320), 0, stream>>>(Z, convw, convb, xhf, Bf, Cf, xhr, Br, Cr);
    // 5. chunk-parallel bidirectional scan
    k_scan_m2_p1<<<dim3(2048), dim3(64), 0, stream>>>(dt, dA, xhf, Bf, Cf, xhr, Br, Cr, m2D,
                                                      yf, yr, Ptbuf, Acbuf, Sloc);
    k_scan_m2_p2<<<dim3(64), dim3(64), 0, stream>>>(Acbuf, Sloc, Sstart);
    // 6. gate + RMS -> gsum
    k_gate<<<dim3(2048), blk, 0, stream>>>(Z, yf, yr, Cf, Cr, Ptbuf, Sstart, normw, gsum);
    // 7. gout = relu(gsum@out_proj)*0.9 + 0.1*X
    mm_f32<2><<<dim3(4, 32), blk, 0, stream>>>(gsum, 256, outprj, 256, gout, 256, 2048, 256, 256, X);
    // 8. fp16 conversions for GCN chain + final projection
    k_adj16<<<dim3(4096), blk, 0, stream>>>(adj, adj16h);
    k_w16t<<<dim3(256), blk, 0, stream>>>(boutW, WT16h);
    // 9. feats[0] = xb (fp32 + fp16^T)
    k_xb_t16<<<dim3(512), blk, 0, stream>>>(X, bn1g, bn1b, feats, fT16h);
    // 10. GCN chain via fp16 MFMA split-K=8
    for (int i = 1; i < 8; ++i) {
        mm16<0><<<dim3(4, 16, 8), blk, 0, stream>>>(adj16h, 2048, fT16h, 2048, psum, nullptr, 256);
        k_combine_t16<<<dim3(512), blk, 0, stream>>>(psum, feats, feats + (size_t)i * 524288, fT16h);
    }
    // 11. xdbl = relu(feats @ xproj_W)
    mm_f32<1><<<dim3(1, 256), blk, 0, stream>>>(feats, 256, xprojW, 48, xdbl, 48, 16384, 48, 256, nullptr);
    // 12. GCN scan -> y (fp32 in-place + fp16 mirror)
    k_scan_gcn<<<dim3(2048), blk, 0, stream>>>(xdbl, dtprjW, bAlog, bD, feats, feats16h);
    // 13. all_out = relu(y @ outproj_W) remap + lastl, via fp16 MFMA
    mm16<3><<<dim3(4, 128, 1), blk, 0, stream>>>(feats16h, 256, WT16h, 256, out, lastl, 256);
    // 14. head
    k_head<<<dim3(2048), blk, 0, stream>>>(lastl, X, gout, bn2g, bn2b, lin2W, out + 4194304);
}

// Round 6
// 259.601 us; speedup vs baseline: 3.3427x; 1.1758x over previous
//
#include <hip/hip_runtime.h>
#include <math.h>

// ---------------------------------------------------------------------------
// GCN_mamba_Net: all matmuls on fp16 MFMA (fp32 accum), chunk-parallel scans.
// N=2048, F_IN=512, D_MODEL=D_INNER=256, NHEADS=32, HDIM=8, D_ST2=8,
// CONV_DIM=272, LAYERS=8, DT_RANK=16, N_STATE=16, NUM_CLASSES=40.
// ---------------------------------------------------------------------------

typedef _Float16 half8 __attribute__((ext_vector_type(8)));
typedef _Float16 half4v __attribute__((ext_vector_type(4)));
typedef float f32x4 __attribute__((ext_vector_type(4)));

__device__ __forceinline__ float softplus_fast(float x) {
    return fmaxf(x, 0.f) + __logf(1.f + __expf(-fabsf(x)));
}
__device__ __forceinline__ float silu_fast(float x) {
    return __fdividef(x, 1.f + __expf(-x));
}

// ---------------------------------------------------------------------------
// fp16 MFMA matmul: C[M,N] = A16[M,K](lda) @ BT16[Npad,K](ldb)^T.
// 256 thr = 4 waves; block tile 128(m) x 64(n); BK=32; 16x16x32 f16 MFMA.
// grid: (ceil(N/64), M/128, KSPLIT); kchunk = K/KSPLIT (mult of 32).
// LDS pad 40 halves/row: 80B stride -> bank stride 20, gcd(20,32)=4 ->
// 8 lanes cover all 32 banks, 2-way over 16 lanes (free per m136).
// EPI: 0 psum partial [kz][M][256]; 1 relu guarded (ldc); 2 gout
//      relu*0.9+0.1*aux; 3 all_out remap + lastl(aux2); 4 fp32+fp16 mirror;
//      5 plain guarded (ldc).
// ---------------------------------------------------------------------------
template<int EPI>
__global__ __launch_bounds__(256) void mm16(
    const _Float16* __restrict__ A16, int lda,
    const _Float16* __restrict__ BT16, int ldb,
    float* __restrict__ dst, _Float16* __restrict__ dst16,
    const float* __restrict__ aux, float* __restrict__ aux2,
    int N, int ldc, int kchunk)
{
    __shared__ _Float16 As[128][40];
    __shared__ _Float16 Bs[64][40];
    const int tid = threadIdx.x;
    const int col0 = blockIdx.x * 64;
    const int row0 = blockIdx.y * 128;
    const int kz = blockIdx.z;
    const int k0 = kz * kchunk;
    const int wave = tid >> 6, lane = tid & 63;
    f32x4 acc[2][4];
    #pragma unroll
    for (int i = 0; i < 2; ++i)
        #pragma unroll
        for (int j = 0; j < 4; ++j)
            acc[i][j] = (f32x4){0.f, 0.f, 0.f, 0.f};
    const int ar = tid >> 1, ac = (tid & 1) * 16;   // A: 2 thr/row, 16 halves each
    const int br = tid >> 2, bc = (tid & 3) * 8;    // B: 4 thr/row, 8 halves each
    const int lrow = lane & 15, kof = (lane >> 4) * 8;
    for (int ks = 0; ks < kchunk; ks += 32) {
        {
            const _Float16* src = A16 + (size_t)(row0 + ar) * lda + k0 + ks + ac;
            *reinterpret_cast<float4*>(&As[ar][ac])     = *reinterpret_cast<const float4*>(src);
            *reinterpret_cast<float4*>(&As[ar][ac + 8]) = *reinterpret_cast<const float4*>(src + 8);
        }
        {
            const _Float16* src = BT16 + (size_t)(col0 + br) * ldb + k0 + ks + bc;
            *reinterpret_cast<float4*>(&Bs[br][bc]) = *reinterpret_cast<const float4*>(src);
        }
        __syncthreads();
        half8 a[2], b[4];
        #pragma unroll
        for (int fr = 0; fr < 2; ++fr)
            a[fr] = *reinterpret_cast<const half8*>(&As[wave * 32 + fr * 16 + lrow][kof]);
        #pragma unroll
        for (int fc = 0; fc < 4; ++fc)
            b[fc] = *reinterpret_cast<const half8*>(&Bs[fc * 16 + lrow][kof]);
        #pragma unroll
        for (int fr = 0; fr < 2; ++fr)
            #pragma unroll
            for (int fc = 0; fc < 4; ++fc)
                acc[fr][fc] = __builtin_amdgcn_mfma_f32_16x16x32_f16(a[fr], b[fc], acc[fr][fc], 0, 0, 0);
        __syncthreads();
    }
    const int col = lane & 15, rbase = (lane >> 4) * 4;
    #pragma unroll
    for (int fr = 0; fr < 2; ++fr)
        #pragma unroll
        for (int fc = 0; fc < 4; ++fc) {
            int c = col0 + fc * 16 + col;
            #pragma unroll
            for (int i = 0; i < 4; ++i) {
                int m = row0 + wave * 32 + fr * 16 + rbase + i;
                float v = acc[fr][fc][i];
                if (EPI == 0) {
                    float* P = dst + (size_t)kz * gridDim.y * 128 * 256;
                    P[(size_t)m * 256 + c] = v;
                } else if (EPI == 1) {
                    if (c < N) dst[(size_t)m * ldc + c] = fmaxf(v, 0.f);
                } else if (EPI == 2) {
                    dst[(size_t)m * 256 + c] = fmaxf(v, 0.f) * 0.9f + 0.1f * aux[(size_t)m * 256 + c];
                } else if (EPI == 3) {
                    int bb = m & 2047, ll = m >> 11;
                    dst[(size_t)((bb << 3) + ll) * 256 + c] = fmaxf(v, 0.f);
                    if (ll == 7) aux2[(size_t)bb * 256 + c] = v;
                } else if (EPI == 4) {
                    dst[(size_t)m * 256 + c] = v;
                    dst16[(size_t)m * 256 + c] = (_Float16)v;
                } else {
                    if (c < N) dst[(size_t)m * ldc + c] = v;
                }
            }
        }
}

// fp32 -> fp16 elementwise (count multiple of 4; 4 per thread)
__global__ __launch_bounds__(256) void k_cvt16(
    const float* __restrict__ in, _Float16* __restrict__ o)
{
    int i = (blockIdx.x * 256 + threadIdx.x) * 4;
    float4 v = *reinterpret_cast<const float4*>(&in[i]);
    half4v h;
    h[0] = (_Float16)v.x; h[1] = (_Float16)v.y; h[2] = (_Float16)v.z; h[3] = (_Float16)v.w;
    *reinterpret_cast<half4v*>(&o[i]) = h;
}

// w [K][N] fp32 -> o [Npad][K] fp16 transposed, zero-padded rows N..Npad.
__global__ __launch_bounds__(256) void k_wt16(
    const float* __restrict__ w, _Float16* __restrict__ o, int K, int N)
{
    int idx = blockIdx.x * 256 + threadIdx.x;
    int n = idx / K, k = idx - n * K;
    o[idx] = (n < N) ? (_Float16)w[(size_t)k * N + n] : (_Float16)0.f;
}

// xb = relu(bn1(X)); write fp32 xb + fp16 mirror + fp16 transposed fT16[n][m]
__global__ __launch_bounds__(256) void k_xb_t16(
    const float* __restrict__ X, const float* __restrict__ g, const float* __restrict__ b,
    float* __restrict__ xb, _Float16* __restrict__ f16a, _Float16* __restrict__ fT16)
{
    const float sc = 0.99999500003749951f;  // 1/sqrt(1+1e-5)
    int m0 = (blockIdx.x >> 3) * 32, n0 = (blockIdx.x & 7) * 32;
    int tx = threadIdx.x & 31, tg = threadIdx.x >> 5;
    __shared__ float T[32][33];
    float gd = g[n0 + tx] * sc, bd = b[n0 + tx];
    #pragma unroll
    for (int i = 0; i < 4; ++i) {
        int m = tg * 4 + i;
        size_t idx = (size_t)(m0 + m) * 256 + n0 + tx;
        float v = fmaxf(X[idx] * gd + bd, 0.f);
        xb[idx] = v;
        f16a[idx] = (_Float16)v;
        T[m][tx] = v;
    }
    __syncthreads();
    #pragma unroll
    for (int j = 0; j < 4; ++j) {
        int n = tg * 4 + j;
        fT16[(size_t)(n0 + n) * 2048 + m0 + tx] = (_Float16)T[tx][n];
    }
}

// xi = 0.95*sum(psum[0..7]) + 0.05*xb; fp32 xi + fp16 mirror + fp16^T fT16
__global__ __launch_bounds__(256) void k_combine_t16(
    const float* __restrict__ psum, const float* __restrict__ xb,
    float* __restrict__ xi, _Float16* __restrict__ xi16, _Float16* __restrict__ fT16)
{
    int m0 = (blockIdx.x >> 3) * 32, n0 = (blockIdx.x & 7) * 32;
    int tx = threadIdx.x & 31, tg = threadIdx.x >> 5;
    __shared__ float T[32][33];
    #pragma unroll
    for (int i = 0; i < 4; ++i) {
        int m = tg * 4 + i;
        size_t idx = (size_t)(m0 + m) * 256 + n0 + tx;
        float s = psum[idx];
        #pragma unroll
        for (int q = 1; q < 8; ++q) s += psum[idx + (size_t)q * 524288];
        float v = 0.95f * s + 0.05f * xb[idx];
        xi[idx] = v;
        xi16[idx] = (_Float16)v;
        T[m][tx] = v;
    }
    __syncthreads();
    #pragma unroll
    for (int j = 0; j < 4; ++j) {
        int n = tg * 4 + j;
        fT16[(size_t)(n0 + n) * 2048 + m0 + tx] = (_Float16)T[tx][n];
    }
}

__global__ __launch_bounds__(256) void k_dtda(
    const float* __restrict__ Z, const float* __restrict__ bias,
    const float* __restrict__ A_log, float* __restrict__ dt, float* __restrict__ dA)
{
    int idx = blockIdx.x * 256 + threadIdx.x;
    if (idx >= 2048 * 32) return;
    int t = idx >> 5, h = idx & 31;
    float v = Z[(size_t)t * 560 + 528 + h] + bias[h];
    float dtv = softplus_fast(v);
    float Ah = -__expf(A_log[h]);
    dt[idx] = dtv;
    dA[idx] = __expf(dtv * Ah);
}

__global__ __launch_bounds__(320) void k_conv(
    const float* __restrict__ Z, const float* __restrict__ w, const float* __restrict__ bconv,
    float* __restrict__ xhf, float* __restrict__ Bf, float* __restrict__ Cf,
    float* __restrict__ xhr, float* __restrict__ Br, float* __restrict__ Cr)
{
    int bx = blockIdx.x;               // 0..4095
    int dir = bx >> 11, t = bx & 2047;
    int c = threadIdx.x;
    if (c >= 272) return;
    float acc = bconv[c];
    #pragma unroll
    for (int k = 0; k < 4; ++k) {
        int tt = dir ? (t + 3 - k) : (t - 3 + k);
        if (tt >= 0 && tt < 2048) acc = fmaf(w[c * 4 + k], Z[(size_t)tt * 560 + 256 + c], acc);
    }
    float v = silu_fast(acc);
    float* xh = dir ? xhr : xhf;
    float* B  = dir ? Br  : Bf;
    float* C  = dir ? Cr  : Cf;
    if (c < 256)       xh[(size_t)t * 256 + c] = v;
    else if (c < 264)  B[(size_t)t * 8 + (c - 256)] = v;
    else               C[(size_t)t * 8 + (c - 264)] = v;
}

// ---------------------------------------------------------------------------
// Chunk-parallel Mamba2 scan (32 chunks of 64 virtual steps).
// ---------------------------------------------------------------------------
__global__ __launch_bounds__(64) void k_scan_m2_p1(
    const float* __restrict__ dt, const float* __restrict__ dA,
    const float* __restrict__ xhf, const float* __restrict__ Bf, const float* __restrict__ Cf,
    const float* __restrict__ xhr, const float* __restrict__ Br, const float* __restrict__ Cr,
    const float* __restrict__ Dvec,
    float* __restrict__ yf, float* __restrict__ yr,
    float* __restrict__ Ptbuf,   // [2][2048][32]
    float* __restrict__ Acbuf,   // [64][32]
    float* __restrict__ Sloc)    // [64][32][64]
{
    int bid = blockIdx.x;        // 0..2047
    int c  = bid & 31;
    int hh = bid >> 5;           // dir*32+h
    int dir = hh >> 5, h = hh & 31;
    const float* xhp = dir ? xhr : xhf;
    const float* Bp  = dir ? Br  : Bf;
    const float* Cp  = dir ? Cr  : Cf;
    float* yp        = dir ? yr  : yf;
    int lane = threadIdx.x;
    int p = lane >> 3, n = lane & 7;
    float Dh = Dvec[h];
    __shared__ float dAs[64];
    __shared__ float Ps[64][8];
    __shared__ float Bs[64][8];
    __shared__ float Cs[64][8];
    __shared__ float Ys[64][8];
    __shared__ float Pts[64];
    const int j0 = c * 64;
    {
        int j = j0 + lane;
        int t = dir ? (2047 - j) : j;
        dAs[lane] = dA[(size_t)t * 32 + h];
    }
    #pragma unroll
    for (int q = 0; q < 8; ++q) {
        int idx = q * 64 + lane;
        int i = idx >> 3, e = idx & 7;
        int j = j0 + i;
        int t = dir ? (2047 - j) : j;
        Ps[i][e] = dt[(size_t)t * 32 + h] * xhp[(size_t)t * 256 + h * 8 + e];
        Bs[i][e] = Bp[(size_t)t * 8 + e];
        Cs[i][e] = Cp[(size_t)t * 8 + e];
    }
    __syncthreads();
    float s = 0.f;
    float P = 1.f;
    for (int i = 0; i < 64; ++i) {
        float a = dAs[i];
        float u = Ps[i][p] * Bs[i][n];
        s = fmaf(a, s, u);
        P *= a;
        float yv = s * Cs[i][n];
        yv += __shfl_xor(yv, 1);
        yv += __shfl_xor(yv, 2);
        yv += __shfl_xor(yv, 4);
        if (n == 0) Ys[i][p] = yv;
        if (lane == 0) Pts[i] = P;
    }
    __syncthreads();
    #pragma unroll
    for (int q = 0; q < 8; ++q) {
        int idx = q * 64 + lane;
        int i = idx >> 3, e = idx & 7;
        int j = j0 + i;
        int t = dir ? (2047 - j) : j;
        yp[(size_t)t * 256 + h * 8 + e] = Ys[i][e] + xhp[(size_t)t * 256 + h * 8 + e] * Dh;
    }
    {
        int j = j0 + lane;
        Ptbuf[((size_t)dir * 2048 + j) * 32 + h] = Pts[lane];
    }
    if (lane == 0) Acbuf[hh * 32 + c] = P;
    Sloc[((size_t)hh * 32 + c) * 64 + lane] = s;
}

__global__ __launch_bounds__(64) void k_scan_m2_p2(
    const float* __restrict__ Acbuf, const float* __restrict__ Sloc,
    float* __restrict__ Sstart)
{
    int hh = blockIdx.x;
    int lane = threadIdx.x;
    float s = 0.f;
    for (int c = 0; c < 32; ++c) {
        Sstart[((size_t)hh * 32 + c) * 64 + lane] = s;
        float a = Acbuf[hh * 32 + c];
        s = fmaf(a, s, Sloc[((size_t)hh * 32 + c) * 64 + lane]);
    }
}

// gating + per-direction RMS norm; emits fp32 gsum + fp16 mirror.
__global__ __launch_bounds__(256) void k_gate(
    const float* __restrict__ Z, const float* __restrict__ yf, const float* __restrict__ yr,
    const float* __restrict__ Cf, const float* __restrict__ Cr,
    const float* __restrict__ Ptbuf, const float* __restrict__ Sstart,
    const float* __restrict__ nw, float* __restrict__ gsum, _Float16* __restrict__ gsum16)
{
    int t = blockIdx.x, d = threadIdx.x;
    int h = d >> 3, p = d & 7;
    __shared__ float Csh[2][8];
    if (d < 8)       Csh[0][d] = Cf[(size_t)t * 8 + d];
    else if (d < 16) Csh[1][d - 8] = Cr[(size_t)t * 8 + (d - 8)];
    __syncthreads();
    int jf = t, jr = 2047 - t;
    int cf = jf >> 6, cr = jr >> 6;
    float Ptf = Ptbuf[((size_t)jf) * 32 + h];
    float Ptr = Ptbuf[((size_t)2048 + jr) * 32 + h];
    const float* ssf = &Sstart[(((size_t)h) * 32 + cf) * 64 + p * 8];
    const float* ssr = &Sstart[(((size_t)(32 + h)) * 32 + cr) * 64 + p * 8];
    float dotf = 0.f, dotr = 0.f;
    #pragma unroll
    for (int n2 = 0; n2 < 8; ++n2) {
        dotf = fmaf(ssf[n2], Csh[0][n2], dotf);
        dotr = fmaf(ssr[n2], Csh[1][n2], dotr);
    }
    float yfv = yf[(size_t)t * 256 + d] + Ptf * dotf;
    float yrv = yr[(size_t)t * 256 + d] + Ptr * dotr;
    float zv = Z[(size_t)t * 560 + d];
    float sz = silu_fast(zv);
    float gf = yfv * sz;
    float gr = yrv * sz;
    float vf = gf * gf, vr = gr * gr;
    for (int o = 32; o > 0; o >>= 1) { vf += __shfl_down(vf, o); vr += __shfl_down(vr, o); }
    __shared__ float sfa[4], sra[4];
    __shared__ float tot[2];
    int wid = d >> 6;
    if ((d & 63) == 0) { sfa[wid] = vf; sra[wid] = vr; }
    __syncthreads();
    if (d == 0) {
        tot[0] = sfa[0] + sfa[1] + sfa[2] + sfa[3];
        tot[1] = sra[0] + sra[1] + sra[2] + sra[3];
    }
    __syncthreads();
    float inf_ = rsqrtf(tot[0] / 256.f + 1e-5f);
    float inr_ = rsqrtf(tot[1] / 256.f + 1e-5f);
    float g = (gf * inf_ + gr * inr_) * nw[d];
    gsum[(size_t)t * 256 + d] = g;
    gsum16[(size_t)t * 256 + d] = (_Float16)g;
}

// GCN-mamba scan; emits fp32 y (in-place) + fp16 mirror (over feats16all).
__global__ __launch_bounds__(256) void k_scan_gcn(
    const float* __restrict__ xdbl,   // [16384][48]
    const float* __restrict__ dtW,    // [16][256]
    const float* __restrict__ A_log,  // [256][16]
    const float* __restrict__ Dv,     // [256]
    float* __restrict__ feats,        // [8][2048][256] in/out
    _Float16* __restrict__ f16o)      // [16384][256] fp16 mirror of y
{
    int b = blockIdx.x, d = threadIdx.x;
    __shared__ float xrow[8][48];
    for (int j = d; j < 384; j += 256) {
        int l = j / 48, k = j % 48;
        xrow[l][k] = xdbl[(size_t)(l * 2048 + b) * 48 + k];
    }
    __syncthreads();
    float a[16];
    #pragma unroll
    for (int n = 0; n < 16; ++n) a[n] = -__expf(A_log[d * 16 + n]);
    float Dd = Dv[d];
    float s[16];
    #pragma unroll
    for (int n = 0; n < 16; ++n) s[n] = 0.f;
    for (int l = 0; l < 8; ++l) {
        float accd = 0.f;
        #pragma unroll
        for (int k = 0; k < 16; ++k) accd = fmaf(xrow[l][k], dtW[k * 256 + d], accd);
        float dl = softplus_fast(accd);
        size_t r = (size_t)(l * 2048 + b) * 256 + d;
        float xv = feats[r];
        float du = dl * xv;
        float y = 0.f;
        #pragma unroll
        for (int n = 0; n < 16; ++n) {
            float dAn = __expf(dl * a[n]);
            s[n] = fmaf(dAn, s[n], du * xrow[l][16 + n]);
            y = fmaf(s[n], xrow[l][32 + n], y);
        }
        float res = y + xv * Dd;
        feats[r] = res;
        f16o[r] = (_Float16)res;
    }
}

__global__ __launch_bounds__(256) void k_head(
    const float* __restrict__ lastl, const float* __restrict__ X, const float* __restrict__ gout,
    const float* __restrict__ g2, const float* __restrict__ b2, const float* __restrict__ W2,
    float* __restrict__ out1)
{
    int b = blockIdx.x, d = threadIdx.x;
    __shared__ float ov[256];
    __shared__ float yv[40];
    const float sc = 0.99999500003749951f;
    float v = (lastl[(size_t)b * 256 + d] + X[(size_t)b * 256 + d]) * 0.5f
              + gout[(size_t)b * 256 + d] * 0.5f;
    v = v * (g2[d] * sc) + b2[d];
    ov[d] = fmaxf(v, 0.f);
    __syncthreads();
    if (d < 40) {
        float acc = 0.f;
        for (int k = 0; k < 256; ++k) acc = fmaf(ov[k], W2[k * 40 + d], acc);
        yv[d] = acc;
    }
    __syncthreads();
    if (d < 40) {
        float m = -1e30f;
        for (int j = 0; j < 40; ++j) m = fmaxf(m, yv[j]);
        float se = 0.f;
        for (int j = 0; j < 40; ++j) se += expf(yv[j] - m);
        out1[(size_t)b * 40 + d] = yv[d] - m - logf(se);
    }
}

// ---------------------------------------------------------------------------
extern "C" void kernel_launch(void* const* d_in, const int* in_sizes, int n_in,
                              void* d_out, int out_size, void* d_ws, size_t ws_size,
                              hipStream_t stream)
{
    const float* x      = (const float*)d_in[0];
    const float* adj    = (const float*)d_in[1];
    const float* lin1W  = (const float*)d_in[2];
    const float* inproj = (const float*)d_in[3];
    const float* convw  = (const float*)d_in[4];
    const float* convb  = (const float*)d_in[5];
    const float* dtbias = (const float*)d_in[6];
    const float* m2Alog = (const float*)d_in[7];
    const float* m2D    = (const float*)d_in[8];
    const float* normw  = (const float*)d_in[9];
    const float* outprj = (const float*)d_in[10];
    const float* xprojW = (const float*)d_in[11];
    const float* dtprjW = (const float*)d_in[12];
    const float* bAlog  = (const float*)d_in[13];
    const float* bD     = (const float*)d_in[14];
    const float* boutW  = (const float*)d_in[15];
    const float* bn1g   = (const float*)d_in[16];
    const float* bn1b   = (const float*)d_in[17];
    const float* bn2g   = (const float*)d_in[18];
    const float* bn2b   = (const float*)d_in[19];
    const float* lin2W  = (const float*)d_in[20];
    float* out = (float*)d_out;
    float* ws  = (float*)d_ws;

    // fp32 buffers
    float* X     = ws + 0;         // 524288
    float* Z     = ws + 524288;    // 1146880
    float* dt    = ws + 1671168;   // 65536
    float* dA    = ws + 1736704;   // 65536
    float* xhf   = ws + 1802240;   // 524288
    float* Bf    = ws + 2326528;   // 16384
    float* Cf    = ws + 2342912;   // 16384
    float* xhr   = ws + 2359296;   // 524288
    float* Br    = ws + 2883584;   // 16384
    float* Cr    = ws + 2899968;   // 16384
    float* yf    = ws + 2916352;   // 524288
    float* yr    = ws + 3440640;   // 524288
    float* gsum  = ws + 3964928;   // 524288
    float* gout  = ws + 4489216;   // 524288
    float* feats = ws + 5013504;   // 4194304
    float* xdbl  = ws + 9207808;   // 786432
    float* lastl = ws + 9994240;   // 524288
    float* psum  = ws + 10518528;  // 8*524288 = 4194304 -> ends 14712832
    // fp16 buffers (halves; float-offset * 2 halves)
    _Float16* adj16h    = (_Float16*)(ws + 14712832);  // 2048x2048
    _Float16* fT16h     = (_Float16*)(ws + 16809984);  // 256x2048 (chain B^T)
    _Float16* WT16h     = (_Float16*)(ws + 17072128);  // boutW^T 256x256
    _Float16* x16       = (_Float16*)(ws + 17104896);  // 2048x512
    _Float16* lin1WT16  = (_Float16*)(ws + 17629184);  // 256x512
    _Float16* inprojT16 = (_Float16*)(ws + 17694720);  // 576x256 (pad)
    _Float16* outprjT16 = (_Float16*)(ws + 17768448);  // 256x256
    _Float16* xprojT16  = (_Float16*)(ws + 17801216);  // 64x256 (pad)
    _Float16* X16       = (_Float16*)(ws + 17809408);  // 2048x256
    _Float16* gsum16    = (_Float16*)(ws + 18071552);  // 2048x256
    _Float16* feats16a  = (_Float16*)(ws + 18333696);  // 16384x256 -> ends 20430848 fl
    // m2-scan scratch aliases psum (dead before GCN chain)
    float* Ptbuf  = psum;               // 131072
    float* Acbuf  = psum + 131072;      // 2048
    float* Sloc   = psum + 133120;      // 131072
    float* Sstart = psum + 264192;      // 131072
    (void)ws_size; (void)in_sizes; (void)n_in; (void)out_size;

    dim3 blk(256);
    // 0. fp16 conversions (inputs/weights)
    k_cvt16<<<dim3(1024), blk, 0, stream>>>(x, x16);
    k_cvt16<<<dim3(4096), blk, 0, stream>>>(adj, adj16h);
    k_wt16<<<dim3(512),  blk, 0, stream>>>(lin1W,  lin1WT16, 512, 256);
    k_wt16<<<dim3(576),  blk, 0, stream>>>(inproj, inprojT16, 256, 560);
    k_wt16<<<dim3(256),  blk, 0, stream>>>(outprj, outprjT16, 256, 256);
    k_wt16<<<dim3(64),   blk, 0, stream>>>(xprojW, xprojT16, 256, 48);
    k_wt16<<<dim3(256),  blk, 0, stream>>>(boutW,  WT16h, 256, 256);
    // 1. X = x @ lin1_W  (fp32 + fp16 mirror)
    mm16<4><<<dim3(4, 16, 1), blk, 0, stream>>>(x16, 512, lin1WT16, 512, X, X16, nullptr, nullptr, 256, 256, 512);
    // 2. Z = X @ in_proj (N=560 guarded)
    mm16<5><<<dim3(9, 16, 1), blk, 0, stream>>>(X16, 256, inprojT16, 256, Z, nullptr, nullptr, nullptr, 560, 560, 256);
    // 3. dt / dA
    k_dtda<<<dim3(256), blk, 0, stream>>>(Z, dtbias, m2Alog, dt, dA);
    // 4. conv (both directions)
    k_conv<<<dim3(4096), dim3(320), 0, stream>>>(Z, convw, convb, xhf, Bf, Cf, xhr, Br, Cr);
    // 5. chunk-parallel bidirectional scan
    k_scan_m2_p1<<<dim3(2048), dim3(64), 0, stream>>>(dt, dA, xhf, Bf, Cf, xhr, Br, Cr, m2D,
                                                      yf, yr, Ptbuf, Acbuf, Sloc);
    k_scan_m2_p2<<<dim3(64), dim3(64), 0, stream>>>(Acbuf, Sloc, Sstart);
    // 6. gate + RMS -> gsum (+fp16)
    k_gate<<<dim3(2048), blk, 0, stream>>>(Z, yf, yr, Cf, Cr, Ptbuf, Sstart, normw, gsum, gsum16);
    // 7. gout = relu(gsum@out_proj)*0.9 + 0.1*X
    mm16<2><<<dim3(4, 16, 1), blk, 0, stream>>>(gsum16, 256, outprjT16, 256, gout, nullptr, X, nullptr, 256, 256, 256);
    // 8. feats[0] = xb (fp32 + fp16 mirror + fp16^T)
    k_xb_t16<<<dim3(512), blk, 0, stream>>>(X, bn1g, bn1b, feats, feats16a, fT16h);
    // 9. GCN chain via fp16 MFMA split-K=8
    for (int i = 1; i < 8; ++i) {
        mm16<0><<<dim3(4, 16, 8), blk, 0, stream>>>(adj16h, 2048, fT16h, 2048, psum, nullptr, nullptr, nullptr, 256, 256, 256);
        k_combine_t16<<<dim3(512), blk, 0, stream>>>(psum, feats, feats + (size_t)i * 524288,
                                                     feats16a + (size_t)i * 524288, fT16h);
    }
    // 10. xdbl = relu(feats @ xproj_W)  (N=48 guarded)
    mm16<1><<<dim3(1, 128, 1), blk, 0, stream>>>(feats16a, 256, xprojT16, 256, xdbl, nullptr, nullptr, nullptr, 48, 48, 256);
    // 11. GCN scan -> y (fp32 in-place + fp16 mirror)
    k_scan_gcn<<<dim3(2048), blk, 0, stream>>>(xdbl, dtprjW, bAlog, bD, feats, feats16a);
    // 12. all_out = relu(y @ outproj_W) remap + lastl
    mm16<3><<<dim3(4, 128, 1), blk, 0, stream>>>(feats16a, 256, WT16h, 256, out, nullptr, nullptr, lastl, 256, 256, 256);
    // 13. head
    k_head<<<dim3(2048), blk, 0, stream>>>(lastl, X, gout, bn2g, bn2b, lin2W, out + 4194304);
}